// Round 1
// baseline (3454.823 us; speedup 1.0000x reference)
//
#include <hip/hip_runtime.h>
#include <math.h>

#define NBATCH 16
#define SEQL   512
#define DIM    41
#define LDFLAT (SEQL*DIM)   // 20992
#define OBS    4096
#define DK     128
#define NH     4
#define DH     32

// ---------------------------------------------------------------------------
// Kernel 1: stable "ones first, zeros after" order per batch + gathered mask
// ---------------------------------------------------------------------------
__global__ __launch_bounds__(1024) void build_order_kernel(
    const float* __restrict__ mask, int* __restrict__ order,
    float* __restrict__ mk_out) {
  int b = blockIdx.x;
  const float* m = mask + (size_t)b * LDFLAT;
  int tid = threadIdx.x;
  int lane = tid & 63, w = tid >> 6;
  __shared__ int wsums[16];
  __shared__ int s_total_ones;
  __shared__ int s_chunk_ones;
  __shared__ int s_ones_base;
  __shared__ int s_zeros_base;

  // phase 1: total number of ones
  int cnt = 0;
  for (int j = tid; j < LDFLAT; j += 1024) cnt += (m[j] > 0.f) ? 1 : 0;
  for (int off = 32; off > 0; off >>= 1) cnt += __shfl_xor(cnt, off);
  if (lane == 0) wsums[w] = cnt;
  __syncthreads();
  if (tid == 0) {
    int t = 0;
    for (int i = 0; i < 16; i++) t += wsums[i];
    s_total_ones = t; s_ones_base = 0; s_zeros_base = 0;
  }
  __syncthreads();
  int total_ones = s_total_ones;

  // phase 2: stable positions via block scan per 1024-chunk
  for (int c0 = 0; c0 < LDFLAT; c0 += 1024) {
    __syncthreads();           // protect base updates / wsums reuse
    int j = c0 + tid;
    bool valid = (j < LDFLAT);
    float mv = valid ? m[j] : 0.f;
    int one = (valid && mv > 0.f) ? 1 : 0;
    // wave inclusive scan
    int v = one;
    for (int off = 1; off < 64; off <<= 1) {
      int t = __shfl_up(v, (unsigned)off);
      if (lane >= off) v += t;
    }
    if (lane == 63) wsums[w] = v;
    __syncthreads();
    if (tid == 0) {
      int run = 0;
      for (int i = 0; i < 16; i++) { int t = wsums[i]; wsums[i] = run; run += t; }
      s_chunk_ones = run;
    }
    __syncthreads();
    int ones_before = (v - one) + wsums[w];
    int ob = s_ones_base, zb = s_zeros_base, chunk_ones = s_chunk_ones;
    int rem = LDFLAT - c0;
    int chunk_valid = rem < 1024 ? rem : 1024;
    int valid_before = tid < rem ? tid : rem;
    if (valid) {
      int pos = one ? (ob + ones_before)
                    : (total_ones + zb + (valid_before - ones_before));
      if (pos < OBS) {
        order[b * OBS + pos] = j;
        mk_out[b * OBS + pos] = mv;
      }
    }
    __syncthreads();
    if (tid == 0) {
      s_ones_base = ob + chunk_ones;
      s_zeros_base = zb + (chunk_valid - chunk_ones);
    }
  }
}

// ---------------------------------------------------------------------------
// Kernel 2: fused gather + embedding  Y = relu(iff_w[c] + t*w41 + u*w42 + b)*mk
// ---------------------------------------------------------------------------
__global__ __launch_bounds__(128) void embed_kernel(
    const int* __restrict__ order, const float* __restrict__ mk_g,
    const float* __restrict__ cx, const float* __restrict__ value,
    const float* __restrict__ iff_w, const float* __restrict__ iff_b,
    float* __restrict__ Z) {
  int idx = blockIdx.x;           // b*OBS + o
  int b = idx >> 12;
  int k = threadIdx.x;
  int j = order[idx];
  int l = j / DIM;
  int d = j - l * DIM;
  float t = cx[b * SEQL + l];
  float u = value[(size_t)b * LDFLAT + j];
  float mk = mk_g[idx];
  float y = iff_w[d * DK + k] + t * iff_w[41 * DK + k] + u * iff_w[42 * DK + k]
          + iff_b[k];
  Z[(size_t)idx * DK + k] = fmaxf(y, 0.f) * mk;
}

// ---------------------------------------------------------------------------
// Kernel 3: projection GEMM  out = X @ W + b, output in head-split layout
// X: rows of 128 (batch stride xbstride elems; 0 => single shared matrix)
// out[((b*NH+h)*N + n)*32 + d]
// ---------------------------------------------------------------------------
__global__ __launch_bounds__(256) void proj_kernel(
    const float* __restrict__ X, const float* __restrict__ W,
    const float* __restrict__ bias, float* __restrict__ out,
    int N, int xbstride) {
  __shared__ __align__(16) float Wl[32 * 128];   // 16KB K-slab of W
  __shared__ __align__(16) float Xl[32][128];    // 16KB, 32 rows
  int tid = threadIdx.x;
  int rb = blockIdx.x * 32;
  for (int i = tid * 4; i < 32 * 128; i += 1024) {
    int rr = i >> 7, k = i & 127;
    int r = rb + rr;
    int b = r / N, n = r - b * N;
    *(float4*)&Xl[rr][k] =
        *(const float4*)&X[(size_t)b * xbstride + (size_t)n * 128 + k];
  }
  int tx = tid & 31, ty = tid >> 5;
  int j0 = tx * 4, r0 = ty * 4;
  float acc[4][4];
#pragma unroll
  for (int i = 0; i < 4; i++)
#pragma unroll
    for (int jj = 0; jj < 4; jj++) acc[i][jj] = 0.f;

  for (int kb = 0; kb < 128; kb += 32) {
    __syncthreads();
    for (int i = tid * 4; i < 32 * 128; i += 1024)
      *(float4*)&Wl[i] = *(const float4*)&W[kb * 128 + i];
    __syncthreads();
#pragma unroll
    for (int kk = 0; kk < 32; kk++) {
      float4 w4 = *(float4*)&Wl[kk * 128 + j0];
#pragma unroll
      for (int i = 0; i < 4; i++) {
        float x = Xl[r0 + i][kb + kk];
        acc[i][0] = fmaf(x, w4.x, acc[i][0]);
        acc[i][1] = fmaf(x, w4.y, acc[i][1]);
        acc[i][2] = fmaf(x, w4.z, acc[i][2]);
        acc[i][3] = fmaf(x, w4.w, acc[i][3]);
      }
    }
  }
  int h = j0 >> 5, d0 = j0 & 31;
  float b0 = bias[j0], b1 = bias[j0 + 1], b2 = bias[j0 + 2], b3 = bias[j0 + 3];
#pragma unroll
  for (int i = 0; i < 4; i++) {
    int r = rb + r0 + i;
    int b = r / N, n = r - b * N;
    float4 res = make_float4(acc[i][0] + b0, acc[i][1] + b1,
                             acc[i][2] + b2, acc[i][3] + b3);
    *(float4*)&out[((size_t)(b * NH + h) * N + n) * DH + d0] = res;
  }
}

// ---------------------------------------------------------------------------
// Kernel 4: flash-style attention.  Oh = Qh + softmax(Q K^T * scale, mask) V
// Qh/Kh/Vh head-split (BH, N, 32).  Writes O plain (B, Nq, 128).
// key_mask: (B, Nk) or null; query_mask: (B, Nq) or null.
// grid (B*NH, Nq/32), block 256 (4 waves, 8 queries/wave)
// ---------------------------------------------------------------------------
__global__ __launch_bounds__(256) void attn_kernel(
    const float* __restrict__ Qh, const float* __restrict__ Kh,
    const float* __restrict__ Vh, const float* __restrict__ key_mask,
    const float* __restrict__ query_mask, float* __restrict__ O,
    int Nq, int Nk, int qbcast) {
  __shared__ float Kl[64 * 33];
  __shared__ float Vl[64 * 33];
  __shared__ float Ql[32 * 33];
  int bh = blockIdx.x;
  int b = bh >> 2, h = bh & 3;
  int q0 = blockIdx.y * 32;
  int tid = threadIdx.x;
  int w = tid >> 6, lane = tid & 63;
  int dloc = lane & 31, halfsel = lane >> 5;

  const float* qbase = Qh + ((size_t)(qbcast ? h : bh) * Nq + q0) * 32;
  for (int i = tid; i < 32 * 32; i += 256) {
    int qq = i >> 5, d = i & 31;
    Ql[qq * 33 + d] = qbase[qq * 32 + d];
  }

  float m_i[8], l_i[8], acc[8];
  bool qvalid[8];
#pragma unroll
  for (int qq = 0; qq < 8; qq++) {
    m_i[qq] = -INFINITY; l_i[qq] = 0.f; acc[qq] = 0.f;
    int q = q0 + w * 8 + qq;
    qvalid[qq] = query_mask ? (query_mask[b * Nq + q] > 0.f) : true;
  }
  const float scale = 0.08838834764831845f;  // 1/sqrt(128)
  const float* kbase = Kh + (size_t)bh * Nk * 32;
  const float* vbase = Vh + (size_t)bh * Nk * 32;

  for (int k0 = 0; k0 < Nk; k0 += 64) {
    __syncthreads();
    for (int i = tid; i < 64 * 32; i += 256) {
      int kk = i >> 5, d = i & 31;
      Kl[kk * 33 + d] = kbase[(size_t)k0 * 32 + i];
      Vl[kk * 33 + d] = vbase[(size_t)k0 * 32 + i];
    }
    __syncthreads();
    float kmv = key_mask ? key_mask[b * Nk + k0 + lane] : 1.f;
#pragma unroll
    for (int qq = 0; qq < 8; qq++) {
      const float* qrow = &Ql[(w * 8 + qq) * 33];
      float s = 0.f;
#pragma unroll
      for (int d = 0; d < 32; d++) s = fmaf(qrow[d], Kl[lane * 33 + d], s);
      s *= scale;
      if (kmv <= 0.f) s = -1e10f;
      if (!qvalid[qq]) s = -1e10f;
      float mx = s;
#pragma unroll
      for (int off = 32; off > 0; off >>= 1) mx = fmaxf(mx, __shfl_xor(mx, off));
      float m_new = fmaxf(m_i[qq], mx);
      float alpha = __expf(m_i[qq] - m_new);
      float p = __expf(s - m_new);
      float ps = p;
#pragma unroll
      for (int off = 32; off > 0; off >>= 1) ps += __shfl_xor(ps, off);
      l_i[qq] = l_i[qq] * alpha + ps;
      m_i[qq] = m_new;
      float a = acc[qq] * alpha;
#pragma unroll
      for (int kk = 0; kk < 32; kk++) {
        float pk = __shfl(p, halfsel * 32 + kk);
        a = fmaf(pk, Vl[(halfsel * 32 + kk) * 33 + dloc], a);
      }
      acc[qq] = a;
    }
  }
#pragma unroll
  for (int qq = 0; qq < 8; qq++) {
    float tot = acc[qq] + __shfl_xor(acc[qq], 32);
    float oval = tot / l_i[qq];
    int q = q0 + w * 8 + qq;
    if (lane < 32) {
      O[((size_t)b * Nq + q) * 128 + h * 32 + dloc] =
          Ql[(w * 8 + qq) * 33 + dloc] + oval;
    }
  }
}

// ---------------------------------------------------------------------------
// Kernel 5: fc_o + epilogue.  final = O + relu(O @ W + b)
// mode 0: Zout = final            (rows of H)
// mode 1: Zout += final * mk[r]   (layer residual)
// ---------------------------------------------------------------------------
__global__ __launch_bounds__(256) void fco_kernel(
    const float* __restrict__ O, const float* __restrict__ W,
    const float* __restrict__ bias, const float* __restrict__ mk,
    float* __restrict__ Zout, int mode) {
  __shared__ __align__(16) float Wl[32 * 128];
  __shared__ __align__(16) float Xl[32][128];
  int tid = threadIdx.x;
  int rb = blockIdx.x * 32;
  for (int i = tid * 4; i < 32 * 128; i += 1024) {
    int rr = i >> 7, k = i & 127;
    *(float4*)&Xl[rr][k] = *(const float4*)&O[(size_t)(rb + rr) * 128 + k];
  }
  int tx = tid & 31, ty = tid >> 5;
  int j0 = tx * 4, r0 = ty * 4;
  float acc[4][4];
#pragma unroll
  for (int i = 0; i < 4; i++)
#pragma unroll
    for (int jj = 0; jj < 4; jj++) acc[i][jj] = 0.f;

  for (int kb = 0; kb < 128; kb += 32) {
    __syncthreads();
    for (int i = tid * 4; i < 32 * 128; i += 1024)
      *(float4*)&Wl[i] = *(const float4*)&W[kb * 128 + i];
    __syncthreads();
#pragma unroll
    for (int kk = 0; kk < 32; kk++) {
      float4 w4 = *(float4*)&Wl[kk * 128 + j0];
#pragma unroll
      for (int i = 0; i < 4; i++) {
        float x = Xl[r0 + i][kb + kk];
        acc[i][0] = fmaf(x, w4.x, acc[i][0]);
        acc[i][1] = fmaf(x, w4.y, acc[i][1]);
        acc[i][2] = fmaf(x, w4.z, acc[i][2]);
        acc[i][3] = fmaf(x, w4.w, acc[i][3]);
      }
    }
  }
  float b0 = bias[j0], b1 = bias[j0 + 1], b2 = bias[j0 + 2], b3 = bias[j0 + 3];
#pragma unroll
  for (int i = 0; i < 4; i++) {
    int r = rb + r0 + i;
    float4 g;
    g.x = fmaxf(acc[i][0] + b0, 0.f) + Xl[r0 + i][j0 + 0];
    g.y = fmaxf(acc[i][1] + b1, 0.f) + Xl[r0 + i][j0 + 1];
    g.z = fmaxf(acc[i][2] + b2, 0.f) + Xl[r0 + i][j0 + 2];
    g.w = fmaxf(acc[i][3] + b3, 0.f) + Xl[r0 + i][j0 + 3];
    float* zp = &Zout[(size_t)r * 128 + j0];
    if (mode) {
      float mkv = mk[r];
      float4 z = *(float4*)zp;
      z.x += g.x * mkv; z.y += g.y * mkv; z.z += g.z * mkv; z.w += g.w * mkv;
      *(float4*)zp = z;
    } else {
      *(float4*)zp = g;
    }
  }
}

// ---------------------------------------------------------------------------
// Kernel 6: write outputs (Z then mk)
// ---------------------------------------------------------------------------
__global__ __launch_bounds__(256) void finalize_kernel(
    const float* __restrict__ Z, const float* __restrict__ mk,
    float* __restrict__ out) {
  size_t i = (size_t)blockIdx.x * 256 + threadIdx.x;
  const size_t nz = (size_t)NBATCH * OBS * DK;
  if (i < nz) out[i] = Z[i];
  else {
    size_t k = i - nz;
    if (k < (size_t)NBATCH * OBS) out[nz + k] = mk[k];
  }
}

// ---------------------------------------------------------------------------
extern "C" void kernel_launch(void* const* d_in, const int* in_sizes, int n_in,
                              void* d_out, int out_size, void* d_ws,
                              size_t ws_size, hipStream_t stream) {
  const float* cx    = (const float*)d_in[0];
  const float* value = (const float*)d_in[1];
  const float* mask  = (const float*)d_in[2];
  const float* iff_w = (const float*)d_in[4];
  const float* iff_b = (const float*)d_in[5];
  const float* indp  = (const float*)d_in[6];
  const float* q0w = (const float*)d_in[7];  const float* q0b = (const float*)d_in[8];
  const float* k0w = (const float*)d_in[9];  const float* k0b = (const float*)d_in[10];
  const float* v0w = (const float*)d_in[11]; const float* v0b = (const float*)d_in[12];
  const float* o0w = (const float*)d_in[13]; const float* o0b = (const float*)d_in[14];
  const float* q1w = (const float*)d_in[15]; const float* q1b = (const float*)d_in[16];
  const float* k1w = (const float*)d_in[17]; const float* k1b = (const float*)d_in[18];
  const float* v1w = (const float*)d_in[19]; const float* v1b = (const float*)d_in[20];
  const float* o1w = (const float*)d_in[21]; const float* o1b = (const float*)d_in[22];

  char* ws = (char*)d_ws;
  int*   order = (int*)ws;    ws += (size_t)NBATCH * OBS * 4;
  float* mk_g  = (float*)ws;  ws += (size_t)NBATCH * OBS * 4;
  float* Z     = (float*)ws;  ws += (size_t)NBATCH * OBS * DK * 4;
  float* big1  = (float*)ws;  ws += (size_t)NBATCH * OBS * DK * 4;
  float* big2  = (float*)ws;  ws += (size_t)NBATCH * OBS * DK * 4;
  float* qh_s  = (float*)ws;  ws += (size_t)NH * 128 * DH * 4;
  float* kh_s  = (float*)ws;  ws += (size_t)NBATCH * NH * 128 * DH * 4;
  float* vh_s  = (float*)ws;  ws += (size_t)NBATCH * NH * 128 * DH * 4;
  float* o_s   = (float*)ws;  ws += (size_t)NBATCH * 128 * DK * 4;
  float* Hbuf  = (float*)ws;  ws += (size_t)NBATCH * 128 * DK * 4;

  build_order_kernel<<<NBATCH, 1024, 0, stream>>>(mask, order, mk_g);
  embed_kernel<<<NBATCH * OBS, 128, 0, stream>>>(order, mk_g, cx, value, iff_w,
                                                 iff_b, Z);

  for (int i = 0; i < 3; i++) {
    const size_t wo = (size_t)i * DK * DK, bo = (size_t)i * DK;
    // ---- MAB1: H = MAB(I, Z), key-masked ----
    proj_kernel<<<128 / 32, 256, 0, stream>>>(indp + (size_t)i * 128 * DK,
                                              q0w + wo, q0b + bo, qh_s, 128, 0);
    proj_kernel<<<NBATCH * OBS / 32, 256, 0, stream>>>(Z, k0w + wo, k0b + bo,
                                                       big1, OBS, OBS * DK);
    proj_kernel<<<NBATCH * OBS / 32, 256, 0, stream>>>(Z, v0w + wo, v0b + bo,
                                                       big2, OBS, OBS * DK);
    attn_kernel<<<dim3(NBATCH * NH, 128 / 32), 256, 0, stream>>>(
        qh_s, big1, big2, mk_g, nullptr, o_s, 128, OBS, 1);
    fco_kernel<<<NBATCH * 128 / 32, 256, 0, stream>>>(o_s, o0w + wo, o0b + bo,
                                                      nullptr, Hbuf, 0);
    // ---- MAB2: Zn = MAB(Z, H), query-masked; Z += Zn*mk ----
    proj_kernel<<<NBATCH * OBS / 32, 256, 0, stream>>>(Z, q1w + wo, q1b + bo,
                                                       big1, OBS, OBS * DK);
    proj_kernel<<<NBATCH * 128 / 32, 256, 0, stream>>>(Hbuf, k1w + wo, k1b + bo,
                                                       kh_s, 128, 128 * DK);
    proj_kernel<<<NBATCH * 128 / 32, 256, 0, stream>>>(Hbuf, v1w + wo, v1b + bo,
                                                       vh_s, 128, 128 * DK);
    attn_kernel<<<dim3(NBATCH * NH, OBS / 32), 256, 0, stream>>>(
        big1, kh_s, vh_s, nullptr, mk_g, big2, OBS, 128, 0);
    fco_kernel<<<NBATCH * OBS / 32, 256, 0, stream>>>(big2, o1w + wo, o1b + bo,
                                                      mk_g, Z, 1);
  }
  size_t total = (size_t)NBATCH * OBS * DK + (size_t)NBATCH * OBS;
  finalize_kernel<<<(int)((total + 255) / 256), 256, 0, stream>>>(
      Z, mk_g, (float*)d_out);
}

// Round 2
// 962.214 us; speedup vs baseline: 3.5905x; 3.5905x over previous
//
#include <hip/hip_runtime.h>
#include <math.h>

#define NBATCH 16
#define SEQL   512
#define DIM    41
#define LDFLAT (SEQL*DIM)   // 20992
#define OBS    4096
#define DK     128
#define NH     4
#define DH     32

typedef short bf16x8 __attribute__((ext_vector_type(8)));
typedef float floatx4 __attribute__((ext_vector_type(4)));

__device__ __forceinline__ short f2bf(float f) {
  union { float f; unsigned u; } v;
  v.f = f;
  unsigned r = (v.u + 0x7fffu + ((v.u >> 16) & 1u)) >> 16;
  return (short)r;
}

// ---------------------------------------------------------------------------
// Kernel 1: stable "ones first, zeros after" order per batch + gathered mask
// ---------------------------------------------------------------------------
__global__ __launch_bounds__(1024) void build_order_kernel(
    const float* __restrict__ mask, int* __restrict__ order,
    float* __restrict__ mk_out) {
  int b = blockIdx.x;
  const float* m = mask + (size_t)b * LDFLAT;
  int tid = threadIdx.x;
  int lane = tid & 63, w = tid >> 6;
  __shared__ int wsums[16];
  __shared__ int s_total_ones;
  __shared__ int s_chunk_ones;
  __shared__ int s_ones_base;
  __shared__ int s_zeros_base;

  int cnt = 0;
  for (int j = tid; j < LDFLAT; j += 1024) cnt += (m[j] > 0.f) ? 1 : 0;
  for (int off = 32; off > 0; off >>= 1) cnt += __shfl_xor(cnt, off);
  if (lane == 0) wsums[w] = cnt;
  __syncthreads();
  if (tid == 0) {
    int t = 0;
    for (int i = 0; i < 16; i++) t += wsums[i];
    s_total_ones = t; s_ones_base = 0; s_zeros_base = 0;
  }
  __syncthreads();
  int total_ones = s_total_ones;

  for (int c0 = 0; c0 < LDFLAT; c0 += 1024) {
    __syncthreads();
    int j = c0 + tid;
    bool valid = (j < LDFLAT);
    float mv = valid ? m[j] : 0.f;
    int one = (valid && mv > 0.f) ? 1 : 0;
    int v = one;
    for (int off = 1; off < 64; off <<= 1) {
      int t = __shfl_up(v, (unsigned)off);
      if (lane >= off) v += t;
    }
    if (lane == 63) wsums[w] = v;
    __syncthreads();
    if (tid == 0) {
      int run = 0;
      for (int i = 0; i < 16; i++) { int t = wsums[i]; wsums[i] = run; run += t; }
      s_chunk_ones = run;
    }
    __syncthreads();
    int ones_before = (v - one) + wsums[w];
    int ob = s_ones_base, zb = s_zeros_base, chunk_ones = s_chunk_ones;
    int rem = LDFLAT - c0;
    int chunk_valid = rem < 1024 ? rem : 1024;
    int valid_before = tid < rem ? tid : rem;
    if (valid) {
      int pos = one ? (ob + ones_before)
                    : (total_ones + zb + (valid_before - ones_before));
      if (pos < OBS) {
        order[b * OBS + pos] = j;
        mk_out[b * OBS + pos] = mv;
      }
    }
    __syncthreads();
    if (tid == 0) {
      s_ones_base = ob + chunk_ones;
      s_zeros_base = zb + (chunk_valid - chunk_ones);
    }
  }
}

// ---------------------------------------------------------------------------
// Kernel 2: fused gather + embedding
// ---------------------------------------------------------------------------
__global__ __launch_bounds__(128) void embed_kernel(
    const int* __restrict__ order, const float* __restrict__ mk_g,
    const float* __restrict__ cx, const float* __restrict__ value,
    const float* __restrict__ iff_w, const float* __restrict__ iff_b,
    float* __restrict__ Z) {
  int idx = blockIdx.x;           // b*OBS + o
  int b = idx >> 12;
  int k = threadIdx.x;
  int j = order[idx];
  int l = j / DIM;
  int d = j - l * DIM;
  float t = cx[b * SEQL + l];
  float u = value[(size_t)b * LDFLAT + j];
  float mk = mk_g[idx];
  float y = iff_w[d * DK + k] + t * iff_w[41 * DK + k] + u * iff_w[42 * DK + k]
          + iff_b[k];
  Z[(size_t)idx * DK + k] = fmaxf(y, 0.f) * mk;
}

// ---------------------------------------------------------------------------
// Kernel 3: projection GEMM  out = X @ W + b, output head-split
// ---------------------------------------------------------------------------
__global__ __launch_bounds__(256) void proj_kernel(
    const float* __restrict__ X, const float* __restrict__ W,
    const float* __restrict__ bias, float* __restrict__ out,
    int N, int xbstride) {
  __shared__ __align__(16) float Wl[32 * 128];
  __shared__ __align__(16) float Xl[32][128];
  int tid = threadIdx.x;
  int rb = blockIdx.x * 32;
  for (int i = tid * 4; i < 32 * 128; i += 1024) {
    int rr = i >> 7, k = i & 127;
    int r = rb + rr;
    int b = r / N, n = r - b * N;
    *(float4*)&Xl[rr][k] =
        *(const float4*)&X[(size_t)b * xbstride + (size_t)n * 128 + k];
  }
  int tx = tid & 31, ty = tid >> 5;
  int j0 = tx * 4, r0 = ty * 4;
  float acc[4][4];
#pragma unroll
  for (int i = 0; i < 4; i++)
#pragma unroll
    for (int jj = 0; jj < 4; jj++) acc[i][jj] = 0.f;

  for (int kb = 0; kb < 128; kb += 32) {
    __syncthreads();
    for (int i = tid * 4; i < 32 * 128; i += 1024)
      *(float4*)&Wl[i] = *(const float4*)&W[kb * 128 + i];
    __syncthreads();
#pragma unroll
    for (int kk = 0; kk < 32; kk++) {
      float4 w4 = *(float4*)&Wl[kk * 128 + j0];
#pragma unroll
      for (int i = 0; i < 4; i++) {
        float x = Xl[r0 + i][kb + kk];
        acc[i][0] = fmaf(x, w4.x, acc[i][0]);
        acc[i][1] = fmaf(x, w4.y, acc[i][1]);
        acc[i][2] = fmaf(x, w4.z, acc[i][2]);
        acc[i][3] = fmaf(x, w4.w, acc[i][3]);
      }
    }
  }
  int h = j0 >> 5, d0 = j0 & 31;
  float b0 = bias[j0], b1 = bias[j0 + 1], b2 = bias[j0 + 2], b3 = bias[j0 + 3];
#pragma unroll
  for (int i = 0; i < 4; i++) {
    int r = rb + r0 + i;
    int b = r / N, n = r - b * N;
    float4 res = make_float4(acc[i][0] + b0, acc[i][1] + b1,
                             acc[i][2] + b2, acc[i][3] + b3);
    *(float4*)&out[((size_t)(b * NH + h) * N + n) * DH + d0] = res;
  }
}

// ---------------------------------------------------------------------------
// Kernel 4a: MAB2 attention (Nq=4096, Nk=128, no masks) via bf16 MFMA.
// grid (64 bh, 64 qtiles), block 256.  O = Q + softmax(QK^T/sqrt(128)) V,
// written plain (B, 4096, 128).
// ---------------------------------------------------------------------------
__global__ __launch_bounds__(256) void attn2_kernel(
    const float* __restrict__ Qh, const float* __restrict__ Kh,
    const float* __restrict__ Vh, float* __restrict__ O) {
  __shared__ __align__(16) short Kl[128 * 40];
  __shared__ __align__(16) short Vt[32 * 136];
  __shared__ __align__(16) short Ql[64 * 40];
  __shared__ __align__(16) float Sl[64 * 132];
  __shared__ __align__(16) short Pl[64 * 136];
  __shared__ float linv[64];
  int bh = blockIdx.x;
  int b = bh >> 2, h = bh & 3;
  int q0 = blockIdx.y * 64;
  int tid = threadIdx.x;
  int wv = tid >> 6, lane = tid & 63, lm = lane & 15, quad = lane >> 4;
  const float* kb = Kh + (size_t)bh * 128 * 32;
  const float* vb = Vh + (size_t)bh * 128 * 32;
  const float* qb = Qh + ((size_t)bh * OBS + q0) * 32;

  for (int i = tid * 4; i < 128 * 32; i += 1024) {
    int r = i >> 5, c = i & 31;
    float4 x = *(const float4*)&kb[i];
    *(short4*)&Kl[r * 40 + c] =
        make_short4(f2bf(x.x), f2bf(x.y), f2bf(x.z), f2bf(x.w));
  }
  for (int i = tid * 4; i < 64 * 32; i += 1024) {
    int r = i >> 5, c = i & 31;
    float4 x = *(const float4*)&qb[i];
    *(short4*)&Ql[r * 40 + c] =
        make_short4(f2bf(x.x), f2bf(x.y), f2bf(x.z), f2bf(x.w));
  }
  for (int i = tid * 4; i < 128 * 32; i += 1024) {
    int r = i >> 5, c = i & 31;
    float4 x = *(const float4*)&vb[i];
    Vt[(c + 0) * 136 + r] = f2bf(x.x);
    Vt[(c + 1) * 136 + r] = f2bf(x.y);
    Vt[(c + 2) * 136 + r] = f2bf(x.z);
    Vt[(c + 3) * 136 + r] = f2bf(x.w);
  }
  __syncthreads();
  // everything below is wave-local in LDS (wave wv owns rows wv*16..wv*16+15)

  const float scale = 0.08838834764831845f;  // 1/sqrt(128)
  bf16x8 afrag = *(bf16x8*)&Ql[(wv * 16 + lm) * 40 + quad * 8];
#pragma unroll
  for (int nt = 0; nt < 8; nt++) {
    bf16x8 bfrag = *(bf16x8*)&Kl[(nt * 16 + lm) * 40 + quad * 8];
    floatx4 c = {0.f, 0.f, 0.f, 0.f};
    c = __builtin_amdgcn_mfma_f32_16x16x32_bf16(afrag, bfrag, c, 0, 0, 0);
#pragma unroll
    for (int r = 0; r < 4; r++)
      Sl[(wv * 16 + quad * 4 + r) * 132 + nt * 16 + lm] = c[r] * scale;
  }

  // softmax: thread handles row tid>>2 (wave-local), quarter tid&3
  {
    int row = tid >> 2, qtr = tid & 3;
    float* srow = &Sl[row * 132 + qtr * 32];
    floatx4 sv[8];
    float mx = -1e30f;
#pragma unroll
    for (int i = 0; i < 8; i++) {
      floatx4 v = *(floatx4*)&srow[i * 4];
      sv[i] = v;
      mx = fmaxf(mx, fmaxf(fmaxf(v[0], v[1]), fmaxf(v[2], v[3])));
    }
    mx = fmaxf(mx, __shfl_xor(mx, 1));
    mx = fmaxf(mx, __shfl_xor(mx, 2));
    float sum = 0.f;
#pragma unroll
    for (int i = 0; i < 8; i++) {
      floatx4 v = sv[i];
      float e0 = __expf(v[0] - mx), e1 = __expf(v[1] - mx);
      float e2 = __expf(v[2] - mx), e3 = __expf(v[3] - mx);
      sum += (e0 + e1) + (e2 + e3);
      *(short4*)&Pl[row * 136 + qtr * 32 + i * 4] =
          make_short4(f2bf(e0), f2bf(e1), f2bf(e2), f2bf(e3));
    }
    sum += __shfl_xor(sum, 1);
    sum += __shfl_xor(sum, 2);
    if (qtr == 0) linv[row] = 1.f / sum;
  }

  // O = P @ V   (M=16/wave, N=32, K=128)
  floatx4 oacc[2] = {{0.f, 0.f, 0.f, 0.f}, {0.f, 0.f, 0.f, 0.f}};
#pragma unroll
  for (int kc = 0; kc < 4; kc++) {
    bf16x8 pf = *(bf16x8*)&Pl[(wv * 16 + lm) * 136 + kc * 32 + quad * 8];
#pragma unroll
    for (int nt2 = 0; nt2 < 2; nt2++) {
      bf16x8 vf = *(bf16x8*)&Vt[(nt2 * 16 + lm) * 136 + kc * 32 + quad * 8];
      oacc[nt2] = __builtin_amdgcn_mfma_f32_16x16x32_bf16(pf, vf, oacc[nt2], 0, 0, 0);
    }
  }
#pragma unroll
  for (int nt2 = 0; nt2 < 2; nt2++) {
#pragma unroll
    for (int r = 0; r < 4; r++) {
      int qrow = wv * 16 + quad * 4 + r;
      float li = linv[qrow];
      size_t gi = ((size_t)b * OBS + q0 + qrow) * 128 + h * 32 + nt2 * 16 + lm;
      O[gi] = qb[(size_t)qrow * 32 + nt2 * 16 + lm] + oacc[nt2][r] * li;
    }
  }
}

// ---------------------------------------------------------------------------
// Kernel 4b: MAB1 attention (Nq=128, Nk=4096, key mask) — flash over 8 key
// splits, online softmax in registers, partial (O,m,l) out.
// grid (64 bh, 8 splits), block 256.
// ---------------------------------------------------------------------------
__global__ __launch_bounds__(256) void attn1_kernel(
    const float* __restrict__ Qh,   // (NH, 128, 32) batch-broadcast
    const float* __restrict__ Kh,   // (64, 4096, 32)
    const float* __restrict__ Vh,
    const float* __restrict__ mk,   // (B, 4096)
    float* __restrict__ Opart, float* __restrict__ mpart,
    float* __restrict__ lpart) {
  __shared__ __align__(16) short Ql[128 * 40];
  __shared__ __align__(16) short Kc[64 * 40];
  __shared__ __align__(16) short Vtc[32 * 72];
  __shared__ __align__(16) short Pl[128 * 72];
  __shared__ float mkc[64];
  int bh = blockIdx.x;
  int b = bh >> 2, h = bh & 3;
  int ks = blockIdx.y;
  int tid = threadIdx.x;
  int wv = tid >> 6, lane = tid & 63, lm = lane & 15, quad = lane >> 4;

  const float* qbg = Qh + (size_t)h * 128 * 32;
  for (int i = tid * 4; i < 128 * 32; i += 1024) {
    int r = i >> 5, c = i & 31;
    float4 x = *(const float4*)&qbg[i];
    *(short4*)&Ql[r * 40 + c] =
        make_short4(f2bf(x.x), f2bf(x.y), f2bf(x.z), f2bf(x.w));
  }
  __syncthreads();
  bf16x8 aq[2];
  aq[0] = *(bf16x8*)&Ql[(wv * 32 + lm) * 40 + quad * 8];
  aq[1] = *(bf16x8*)&Ql[(wv * 32 + 16 + lm) * 40 + quad * 8];

  float m_i[2][4], l_i[2][4];
  floatx4 oacc[2][2];
#pragma unroll
  for (int mt = 0; mt < 2; mt++) {
#pragma unroll
    for (int r = 0; r < 4; r++) { m_i[mt][r] = -1e30f; l_i[mt][r] = 0.f; }
    oacc[mt][0] = (floatx4){0.f, 0.f, 0.f, 0.f};
    oacc[mt][1] = (floatx4){0.f, 0.f, 0.f, 0.f};
  }
  const float scale = 0.08838834764831845f;
  const float* kbase = Kh + ((size_t)bh * OBS + ks * 512) * 32;
  const float* vbase = Vh + ((size_t)bh * OBS + ks * 512) * 32;
  const float* mkb = mk + (size_t)b * OBS + ks * 512;

  for (int ch = 0; ch < 8; ch++) {
    __syncthreads();
    for (int i = tid * 4; i < 64 * 32; i += 1024) {
      int r = i >> 5, c = i & 31;
      float4 x = *(const float4*)&kbase[ch * 2048 + i];
      *(short4*)&Kc[r * 40 + c] =
          make_short4(f2bf(x.x), f2bf(x.y), f2bf(x.z), f2bf(x.w));
      float4 y = *(const float4*)&vbase[ch * 2048 + i];
      Vtc[(c + 0) * 72 + r] = f2bf(y.x);
      Vtc[(c + 1) * 72 + r] = f2bf(y.y);
      Vtc[(c + 2) * 72 + r] = f2bf(y.z);
      Vtc[(c + 3) * 72 + r] = f2bf(y.w);
    }
    if (tid < 64) mkc[tid] = mkb[ch * 64 + tid];
    __syncthreads();

    // S = Q K^T for 64-key chunk
    floatx4 sf[2][4];
#pragma unroll
    for (int nt = 0; nt < 4; nt++) {
      bf16x8 bfrag = *(bf16x8*)&Kc[(nt * 16 + lm) * 40 + quad * 8];
      floatx4 z = {0.f, 0.f, 0.f, 0.f};
      sf[0][nt] = __builtin_amdgcn_mfma_f32_16x16x32_bf16(aq[0], bfrag, z, 0, 0, 0);
      sf[1][nt] = __builtin_amdgcn_mfma_f32_16x16x32_bf16(aq[1], bfrag, z, 0, 0, 0);
    }
    // mask + scale
#pragma unroll
    for (int nt = 0; nt < 4; nt++) {
      float mkv = mkc[nt * 16 + lm];
      bool ok = mkv > 0.f;
#pragma unroll
      for (int mt = 0; mt < 2; mt++)
#pragma unroll
        for (int r = 0; r < 4; r++)
          sf[mt][nt][r] = ok ? sf[mt][nt][r] * scale : -1e10f;
    }
    // online softmax (rows = quad*4+r, reduce across 16-lane quad group)
#pragma unroll
    for (int mt = 0; mt < 2; mt++) {
#pragma unroll
      for (int r = 0; r < 4; r++) {
        float mx = fmaxf(fmaxf(sf[mt][0][r], sf[mt][1][r]),
                         fmaxf(sf[mt][2][r], sf[mt][3][r]));
        mx = fmaxf(mx, __shfl_xor(mx, 1));
        mx = fmaxf(mx, __shfl_xor(mx, 2));
        mx = fmaxf(mx, __shfl_xor(mx, 4));
        mx = fmaxf(mx, __shfl_xor(mx, 8));
        float mn = fmaxf(m_i[mt][r], mx);
        float al = __expf(m_i[mt][r] - mn);
        float ps = 0.f;
#pragma unroll
        for (int nt = 0; nt < 4; nt++) {
          float p = __expf(sf[mt][nt][r] - mn);
          sf[mt][nt][r] = p;
          ps += p;
        }
        ps += __shfl_xor(ps, 1);
        ps += __shfl_xor(ps, 2);
        ps += __shfl_xor(ps, 4);
        ps += __shfl_xor(ps, 8);
        l_i[mt][r] = l_i[mt][r] * al + ps;
        m_i[mt][r] = mn;
        oacc[mt][0] *= al;
        oacc[mt][1] *= al;
      }
    }
    // P -> LDS (bf16), wave-local rows
#pragma unroll
    for (int mt = 0; mt < 2; mt++)
#pragma unroll
      for (int nt = 0; nt < 4; nt++)
#pragma unroll
        for (int r = 0; r < 4; r++)
          Pl[(wv * 32 + mt * 16 + quad * 4 + r) * 72 + nt * 16 + lm] =
              f2bf(sf[mt][nt][r]);
    // O += P @ V
#pragma unroll
    for (int kc = 0; kc < 2; kc++) {
      bf16x8 vf0 = *(bf16x8*)&Vtc[lm * 72 + kc * 32 + quad * 8];
      bf16x8 vf1 = *(bf16x8*)&Vtc[(16 + lm) * 72 + kc * 32 + quad * 8];
#pragma unroll
      for (int mt = 0; mt < 2; mt++) {
        bf16x8 pf = *(bf16x8*)&Pl[(wv * 32 + mt * 16 + lm) * 72 + kc * 32 + quad * 8];
        oacc[mt][0] = __builtin_amdgcn_mfma_f32_16x16x32_bf16(pf, vf0, oacc[mt][0], 0, 0, 0);
        oacc[mt][1] = __builtin_amdgcn_mfma_f32_16x16x32_bf16(pf, vf1, oacc[mt][1], 0, 0, 0);
      }
    }
  }
  // write partials (un-normalized)
  float* ob = Opart + (size_t)(ks * 64 + bh) * 128 * 32;
#pragma unroll
  for (int mt = 0; mt < 2; mt++) {
#pragma unroll
    for (int r = 0; r < 4; r++) {
      int row = wv * 32 + mt * 16 + quad * 4 + r;
      ob[(size_t)row * 32 + lm] = oacc[mt][0][r];
      ob[(size_t)row * 32 + 16 + lm] = oacc[mt][1][r];
      if (lm == 0) {
        mpart[(size_t)(ks * 64 + bh) * 128 + row] = m_i[mt][r];
        lpart[(size_t)(ks * 64 + bh) * 128 + row] = l_i[mt][r];
      }
    }
  }
}

// combine 8 key-split partials -> O (B,128,128) with Q residual
__global__ __launch_bounds__(256) void attn1_combine_kernel(
    const float* __restrict__ Opart, const float* __restrict__ mpart,
    const float* __restrict__ lpart, const float* __restrict__ Qh,
    float* __restrict__ O) {
  int bh = blockIdx.x;
  int b = bh >> 2, h = bh & 3;
  int q = blockIdx.y * 8 + (threadIdx.x >> 5);
  int d = threadIdx.x & 31;
  float mv[8], lv[8], m = -1e30f;
#pragma unroll
  for (int s = 0; s < 8; s++) {
    mv[s] = mpart[(size_t)(s * 64 + bh) * 128 + q];
    lv[s] = lpart[(size_t)(s * 64 + bh) * 128 + q];
    m = fmaxf(m, mv[s]);
  }
  float l = 0.f, o = 0.f;
#pragma unroll
  for (int s = 0; s < 8; s++) {
    float w = __expf(mv[s] - m);
    l += lv[s] * w;
    o += Opart[((size_t)(s * 64 + bh) * 128 + q) * 32 + d] * w;
  }
  O[((size_t)b * 128 + q) * 128 + h * 32 + d] =
      Qh[((size_t)h * 128 + q) * 32 + d] + o / l;
}

// ---------------------------------------------------------------------------
// Kernel 5: fc_o + epilogue.  final = O + relu(O @ W + b)
// ---------------------------------------------------------------------------
__global__ __launch_bounds__(256) void fco_kernel(
    const float* __restrict__ O, const float* __restrict__ W,
    const float* __restrict__ bias, const float* __restrict__ mk,
    float* __restrict__ Zout, int mode) {
  __shared__ __align__(16) float Wl[32 * 128];
  __shared__ __align__(16) float Xl[32][128];
  int tid = threadIdx.x;
  int rb = blockIdx.x * 32;
  for (int i = tid * 4; i < 32 * 128; i += 1024) {
    int rr = i >> 7, k = i & 127;
    *(float4*)&Xl[rr][k] = *(const float4*)&O[(size_t)(rb + rr) * 128 + k];
  }
  int tx = tid & 31, ty = tid >> 5;
  int j0 = tx * 4, r0 = ty * 4;
  float acc[4][4];
#pragma unroll
  for (int i = 0; i < 4; i++)
#pragma unroll
    for (int jj = 0; jj < 4; jj++) acc[i][jj] = 0.f;

  for (int kb = 0; kb < 128; kb += 32) {
    __syncthreads();
    for (int i = tid * 4; i < 32 * 128; i += 1024)
      *(float4*)&Wl[i] = *(const float4*)&W[kb * 128 + i];
    __syncthreads();
#pragma unroll
    for (int kk = 0; kk < 32; kk++) {
      float4 w4 = *(float4*)&Wl[kk * 128 + j0];
#pragma unroll
      for (int i = 0; i < 4; i++) {
        float x = Xl[r0 + i][kb + kk];
        acc[i][0] = fmaf(x, w4.x, acc[i][0]);
        acc[i][1] = fmaf(x, w4.y, acc[i][1]);
        acc[i][2] = fmaf(x, w4.z, acc[i][2]);
        acc[i][3] = fmaf(x, w4.w, acc[i][3]);
      }
    }
  }
  float b0 = bias[j0], b1 = bias[j0 + 1], b2 = bias[j0 + 2], b3 = bias[j0 + 3];
#pragma unroll
  for (int i = 0; i < 4; i++) {
    int r = rb + r0 + i;
    float4 g;
    g.x = fmaxf(acc[i][0] + b0, 0.f) + Xl[r0 + i][j0 + 0];
    g.y = fmaxf(acc[i][1] + b1, 0.f) + Xl[r0 + i][j0 + 1];
    g.z = fmaxf(acc[i][2] + b2, 0.f) + Xl[r0 + i][j0 + 2];
    g.w = fmaxf(acc[i][3] + b3, 0.f) + Xl[r0 + i][j0 + 3];
    float* zp = &Zout[(size_t)r * 128 + j0];
    if (mode) {
      float mkv = mk[r];
      float4 z = *(float4*)zp;
      z.x += g.x * mkv; z.y += g.y * mkv; z.z += g.z * mkv; z.w += g.w * mkv;
      *(float4*)zp = z;
    } else {
      *(float4*)zp = g;
    }
  }
}

// ---------------------------------------------------------------------------
__global__ __launch_bounds__(256) void finalize_kernel(
    const float* __restrict__ Z, const float* __restrict__ mk,
    float* __restrict__ out) {
  size_t i = (size_t)blockIdx.x * 256 + threadIdx.x;
  const size_t nz = (size_t)NBATCH * OBS * DK;
  if (i < nz) out[i] = Z[i];
  else {
    size_t k = i - nz;
    if (k < (size_t)NBATCH * OBS) out[nz + k] = mk[k];
  }
}

// ---------------------------------------------------------------------------
extern "C" void kernel_launch(void* const* d_in, const int* in_sizes, int n_in,
                              void* d_out, int out_size, void* d_ws,
                              size_t ws_size, hipStream_t stream) {
  const float* cx    = (const float*)d_in[0];
  const float* value = (const float*)d_in[1];
  const float* mask  = (const float*)d_in[2];
  const float* iff_w = (const float*)d_in[4];
  const float* iff_b = (const float*)d_in[5];
  const float* indp  = (const float*)d_in[6];
  const float* q0w = (const float*)d_in[7];  const float* q0b = (const float*)d_in[8];
  const float* k0w = (const float*)d_in[9];  const float* k0b = (const float*)d_in[10];
  const float* v0w = (const float*)d_in[11]; const float* v0b = (const float*)d_in[12];
  const float* o0w = (const float*)d_in[13]; const float* o0b = (const float*)d_in[14];
  const float* q1w = (const float*)d_in[15]; const float* q1b = (const float*)d_in[16];
  const float* k1w = (const float*)d_in[17]; const float* k1b = (const float*)d_in[18];
  const float* v1w = (const float*)d_in[19]; const float* v1b = (const float*)d_in[20];
  const float* o1w = (const float*)d_in[21]; const float* o1b = (const float*)d_in[22];

  char* ws = (char*)d_ws;
  int*   order = (int*)ws;    ws += (size_t)NBATCH * OBS * 4;
  float* mk_g  = (float*)ws;  ws += (size_t)NBATCH * OBS * 4;
  float* Z     = (float*)ws;  ws += (size_t)NBATCH * OBS * DK * 4;
  float* big1  = (float*)ws;  ws += (size_t)NBATCH * OBS * DK * 4;
  float* big2  = (float*)ws;  ws += (size_t)NBATCH * OBS * DK * 4;
  float* qh_s  = (float*)ws;  ws += (size_t)NH * 128 * DH * 4;
  float* kh_s  = (float*)ws;  ws += (size_t)NBATCH * NH * 128 * DH * 4;
  float* vh_s  = (float*)ws;  ws += (size_t)NBATCH * NH * 128 * DH * 4;
  float* o_s   = (float*)ws;  ws += (size_t)NBATCH * 128 * DK * 4;
  float* Hbuf  = (float*)ws;  ws += (size_t)NBATCH * 128 * DK * 4;
  float* Opart = (float*)ws;  ws += (size_t)8 * 64 * 128 * 32 * 4;
  float* mpart = (float*)ws;  ws += (size_t)8 * 64 * 128 * 4;
  float* lpart = (float*)ws;  ws += (size_t)8 * 64 * 128 * 4;

  build_order_kernel<<<NBATCH, 1024, 0, stream>>>(mask, order, mk_g);
  embed_kernel<<<NBATCH * OBS, 128, 0, stream>>>(order, mk_g, cx, value, iff_w,
                                                 iff_b, Z);

  for (int i = 0; i < 3; i++) {
    const size_t wo = (size_t)i * DK * DK, bo = (size_t)i * DK;
    // ---- MAB1: H = MAB(I, Z), key-masked ----
    proj_kernel<<<128 / 32, 256, 0, stream>>>(indp + (size_t)i * 128 * DK,
                                              q0w + wo, q0b + bo, qh_s, 128, 0);
    proj_kernel<<<NBATCH * OBS / 32, 256, 0, stream>>>(Z, k0w + wo, k0b + bo,
                                                       big1, OBS, OBS * DK);
    proj_kernel<<<NBATCH * OBS / 32, 256, 0, stream>>>(Z, v0w + wo, v0b + bo,
                                                       big2, OBS, OBS * DK);
    attn1_kernel<<<dim3(NBATCH * NH, 8), 256, 0, stream>>>(
        qh_s, big1, big2, mk_g, Opart, mpart, lpart);
    attn1_combine_kernel<<<dim3(NBATCH * NH, 16), 256, 0, stream>>>(
        Opart, mpart, lpart, qh_s, o_s);
    fco_kernel<<<NBATCH * 128 / 32, 256, 0, stream>>>(o_s, o0w + wo, o0b + bo,
                                                      nullptr, Hbuf, 0);
    // ---- MAB2: Zn = MAB(Z, H); Z += Zn*mk ----
    proj_kernel<<<NBATCH * OBS / 32, 256, 0, stream>>>(Z, q1w + wo, q1b + bo,
                                                       big1, OBS, OBS * DK);
    proj_kernel<<<NBATCH * 128 / 32, 256, 0, stream>>>(Hbuf, k1w + wo, k1b + bo,
                                                       kh_s, 128, 128 * DK);
    proj_kernel<<<NBATCH * 128 / 32, 256, 0, stream>>>(Hbuf, v1w + wo, v1b + bo,
                                                       vh_s, 128, 128 * DK);
    attn2_kernel<<<dim3(NBATCH * NH, OBS / 64), 256, 0, stream>>>(
        big1, kh_s, vh_s, big2);
    fco_kernel<<<NBATCH * OBS / 32, 256, 0, stream>>>(big2, o1w + wo, o1b + bo,
                                                      mk_g, Z, 1);
  }
  size_t total = (size_t)NBATCH * OBS * DK + (size_t)NBATCH * OBS;
  finalize_kernel<<<(int)((total + 255) / 256), 256, 0, stream>>>(
      Z, mk_g, (float*)d_out);
}

// Round 3
// 623.710 us; speedup vs baseline: 5.5392x; 1.5427x over previous
//
#include <hip/hip_runtime.h>
#include <math.h>

#define NBATCH 16
#define SEQL   512
#define DIM    41
#define LDFLAT (SEQL*DIM)   // 20992
#define OBS    4096
#define DK     128
#define NH     4
#define DH     32

typedef short bf16x8 __attribute__((ext_vector_type(8)));
typedef short short8v __attribute__((ext_vector_type(8)));
typedef float floatx4 __attribute__((ext_vector_type(4)));

__device__ __forceinline__ short f2bf(float f) {
  union { float f; unsigned u; } v;
  v.f = f;
  unsigned r = (v.u + 0x7fffu + ((v.u >> 16) & 1u)) >> 16;
  return (short)r;
}
__device__ __forceinline__ float bf2f(short s) {
  union { unsigned u; float f; } v;
  v.u = ((unsigned)(unsigned short)s) << 16;
  return v.f;
}

// ---------------------------------------------------------------------------
// Kernel 0: weights -> bf16, transposed to Wt[n][k]. grid 24 (= layer*8+wi)
// ---------------------------------------------------------------------------
__global__ __launch_bounds__(256) void prep_weights_kernel(
    const float* __restrict__ q0w, const float* __restrict__ k0w,
    const float* __restrict__ v0w, const float* __restrict__ o0w,
    const float* __restrict__ q1w, const float* __restrict__ k1w,
    const float* __restrict__ v1w, const float* __restrict__ o1w,
    short* __restrict__ Wt) {
  __shared__ float Tl[128 * 132];
  int id = blockIdx.x, l = id >> 3, wi = id & 7;
  const float* s;
  switch (wi) {
    case 0: s = q0w; break; case 1: s = k0w; break;
    case 2: s = v0w; break; case 3: s = o0w; break;
    case 4: s = q1w; break; case 5: s = k1w; break;
    case 6: s = v1w; break; default: s = o1w; break;
  }
  s += (size_t)l * 16384;
  int tid = threadIdx.x;
  for (int i = tid * 4; i < 16384; i += 1024) {
    int k = i >> 7, n = i & 127;
    float4 x = *(const float4*)&s[i];
    Tl[k * 132 + n + 0] = x.x; Tl[k * 132 + n + 1] = x.y;
    Tl[k * 132 + n + 2] = x.z; Tl[k * 132 + n + 3] = x.w;
  }
  __syncthreads();
  short* dst = Wt + (size_t)id * 16384;
  int n = tid >> 1, k0 = (tid & 1) * 64;
  for (int jc = 0; jc < 8; jc++) {
    short8v t;
#pragma unroll
    for (int j = 0; j < 8; j++) t[j] = f2bf(Tl[(k0 + jc * 8 + j) * 132 + n]);
    *(short8v*)&dst[n * 128 + k0 + jc * 8] = t;
  }
}

// ---------------------------------------------------------------------------
// Kernel 1: stable order + gathered mask (also writes mk into d_out tail)
// ---------------------------------------------------------------------------
__global__ __launch_bounds__(1024) void build_order_kernel(
    const float* __restrict__ mask, int* __restrict__ order,
    float* __restrict__ mk_out, float* __restrict__ mk_out2) {
  int b = blockIdx.x;
  const float* m = mask + (size_t)b * LDFLAT;
  int tid = threadIdx.x;
  int lane = tid & 63, w = tid >> 6;
  __shared__ int wsums[16];
  __shared__ int s_total_ones;
  __shared__ int s_chunk_ones;
  __shared__ int s_ones_base;
  __shared__ int s_zeros_base;

  int cnt = 0;
  for (int j = tid; j < LDFLAT; j += 1024) cnt += (m[j] > 0.f) ? 1 : 0;
  for (int off = 32; off > 0; off >>= 1) cnt += __shfl_xor(cnt, off);
  if (lane == 0) wsums[w] = cnt;
  __syncthreads();
  if (tid == 0) {
    int t = 0;
    for (int i = 0; i < 16; i++) t += wsums[i];
    s_total_ones = t; s_ones_base = 0; s_zeros_base = 0;
  }
  __syncthreads();
  int total_ones = s_total_ones;

  for (int c0 = 0; c0 < LDFLAT; c0 += 1024) {
    __syncthreads();
    int j = c0 + tid;
    bool valid = (j < LDFLAT);
    float mv = valid ? m[j] : 0.f;
    int one = (valid && mv > 0.f) ? 1 : 0;
    int v = one;
    for (int off = 1; off < 64; off <<= 1) {
      int t = __shfl_up(v, (unsigned)off);
      if (lane >= off) v += t;
    }
    if (lane == 63) wsums[w] = v;
    __syncthreads();
    if (tid == 0) {
      int run = 0;
      for (int i = 0; i < 16; i++) { int t = wsums[i]; wsums[i] = run; run += t; }
      s_chunk_ones = run;
    }
    __syncthreads();
    int ones_before = (v - one) + wsums[w];
    int ob = s_ones_base, zb = s_zeros_base, chunk_ones = s_chunk_ones;
    int rem = LDFLAT - c0;
    int chunk_valid = rem < 1024 ? rem : 1024;
    int valid_before = tid < rem ? tid : rem;
    if (valid) {
      int pos = one ? (ob + ones_before)
                    : (total_ones + zb + (valid_before - ones_before));
      if (pos < OBS) {
        order[b * OBS + pos] = j;
        mk_out[b * OBS + pos] = mv;
        mk_out2[b * OBS + pos] = mv;
      }
    }
    __syncthreads();
    if (tid == 0) {
      s_ones_base = ob + chunk_ones;
      s_zeros_base = zb + (chunk_valid - chunk_ones);
    }
  }
}

// ---------------------------------------------------------------------------
// Kernel 2: fused gather + embedding (fp32 Z)
// ---------------------------------------------------------------------------
__global__ __launch_bounds__(128) void embed_kernel(
    const int* __restrict__ order, const float* __restrict__ mk_g,
    const float* __restrict__ cx, const float* __restrict__ value,
    const float* __restrict__ iff_w, const float* __restrict__ iff_b,
    float* __restrict__ Z) {
  int idx = blockIdx.x;
  int b = idx >> 12;
  int k = threadIdx.x;
  int j = order[idx];
  int l = j / DIM;
  int d = j - l * DIM;
  float t = cx[b * SEQL + l];
  float u = value[(size_t)b * LDFLAT + j];
  float mk = mk_g[idx];
  float y = iff_w[d * DK + k] + t * iff_w[41 * DK + k] + u * iff_w[42 * DK + k]
          + iff_b[k];
  Z[(size_t)idx * DK + k] = fmaxf(y, 0.f) * mk;
}

// ---------------------------------------------------------------------------
// Kernel 3: MFMA projection. X fp32 (rows,128) -> up to two bf16 head-split
// outputs out[((b*NH+h)*N + n)*32 + d], N = 1<<nshift. 64 rows/block.
// ---------------------------------------------------------------------------
__global__ __launch_bounds__(256) void mfma_proj_kernel(
    const float* __restrict__ X, const short* __restrict__ Wt1,
    const float* __restrict__ b1, short* __restrict__ out1,
    const short* __restrict__ Wt2, const float* __restrict__ b2,
    short* __restrict__ out2, int nshift) {
  __shared__ __align__(16) short Xl[64 * 136];
  __shared__ __align__(16) short Wl[128 * 136];
  int tid = threadIdx.x;
  int rb = blockIdx.x * 64;
  for (int i = tid * 4; i < 64 * 128; i += 1024) {
    int rr = i >> 7, c = i & 127;
    float4 x = *(const float4*)&X[(size_t)(rb + rr) * 128 + c];
    *(short4*)&Xl[rr * 136 + c] =
        make_short4(f2bf(x.x), f2bf(x.y), f2bf(x.z), f2bf(x.w));
  }
  for (int i = tid * 8; i < 128 * 128; i += 2048)
    *(int4*)&Wl[(i >> 7) * 136 + (i & 127)] = *(const int4*)&Wt1[i];
  __syncthreads();
  int wv = tid >> 6, lane = tid & 63, lm = lane & 15, quad = lane >> 4;
  bf16x8 af[4];
#pragma unroll
  for (int kc = 0; kc < 4; kc++)
    af[kc] = *(bf16x8*)&Xl[(wv * 16 + lm) * 136 + kc * 32 + quad * 8];

  floatx4 acc[8];
#pragma unroll
  for (int nt = 0; nt < 8; nt++) acc[nt] = (floatx4){0.f, 0.f, 0.f, 0.f};
#pragma unroll
  for (int kc = 0; kc < 4; kc++) {
    bf16x8 a = af[kc];
#pragma unroll
    for (int nt = 0; nt < 8; nt++) {
      bf16x8 bfr = *(bf16x8*)&Wl[(nt * 16 + lm) * 136 + kc * 32 + quad * 8];
      acc[nt] = __builtin_amdgcn_mfma_f32_16x16x32_bf16(a, bfr, acc[nt], 0, 0, 0);
    }
  }
  __syncthreads();
  short* Sl = Wl;
#pragma unroll
  for (int nt = 0; nt < 8; nt++) {
    int col = nt * 16 + lm;
    float bn = b1[col];
#pragma unroll
    for (int r = 0; r < 4; r++)
      Sl[(wv * 16 + quad * 4 + r) * 136 + col] = f2bf(acc[nt][r] + bn);
  }
  __syncthreads();
  {
    int rr = tid >> 2, hh = tid & 3;
    int r = rb + rr;
    int bb = r >> nshift, nn = r & ((1 << nshift) - 1);
    size_t o = ((size_t)(bb * NH + hh) * (1 << nshift) + nn) * 32;
#pragma unroll
    for (int j = 0; j < 4; j++)
      *(int4*)&out1[o + j * 8] = *(int4*)&Sl[rr * 136 + hh * 32 + j * 8];
  }
  if (Wt2) {
    __syncthreads();
    for (int i = tid * 8; i < 128 * 128; i += 2048)
      *(int4*)&Wl[(i >> 7) * 136 + (i & 127)] = *(const int4*)&Wt2[i];
    __syncthreads();
#pragma unroll
    for (int nt = 0; nt < 8; nt++) acc[nt] = (floatx4){0.f, 0.f, 0.f, 0.f};
#pragma unroll
    for (int kc = 0; kc < 4; kc++) {
      bf16x8 a = af[kc];
#pragma unroll
      for (int nt = 0; nt < 8; nt++) {
        bf16x8 bfr = *(bf16x8*)&Wl[(nt * 16 + lm) * 136 + kc * 32 + quad * 8];
        acc[nt] = __builtin_amdgcn_mfma_f32_16x16x32_bf16(a, bfr, acc[nt], 0, 0, 0);
      }
    }
    __syncthreads();
#pragma unroll
    for (int nt = 0; nt < 8; nt++) {
      int col = nt * 16 + lm;
      float bn = b2[col];
#pragma unroll
      for (int r = 0; r < 4; r++)
        Sl[(wv * 16 + quad * 4 + r) * 136 + col] = f2bf(acc[nt][r] + bn);
    }
    __syncthreads();
    int rr = tid >> 2, hh = tid & 3;
    int r = rb + rr;
    int bb = r >> nshift, nn = r & ((1 << nshift) - 1);
    size_t o = ((size_t)(bb * NH + hh) * (1 << nshift) + nn) * 32;
#pragma unroll
    for (int j = 0; j < 4; j++)
      *(int4*)&out2[o + j * 8] = *(int4*)&Sl[rr * 136 + hh * 32 + j * 8];
  }
}

// ---------------------------------------------------------------------------
// Kernel 4a: MAB2 attention, bf16 in/out.  grid (64 bh, 64 qtiles), block 256.
// ---------------------------------------------------------------------------
__global__ __launch_bounds__(256) void attn2_kernel(
    const short* __restrict__ Qh, const short* __restrict__ Kh,
    const short* __restrict__ Vh, short* __restrict__ O) {
  __shared__ __align__(16) short Kl[128 * 40];
  __shared__ __align__(16) short Vt[32 * 136];
  __shared__ __align__(16) short Ql[64 * 40];
  __shared__ __align__(16) float Sl[64 * 132];
  __shared__ __align__(16) short Pl[64 * 136];
  __shared__ float linv[64];
  int bh = blockIdx.x;
  int b = bh >> 2, h = bh & 3;
  int q0 = blockIdx.y * 64;
  int tid = threadIdx.x;
  int wv = tid >> 6, lane = tid & 63, lm = lane & 15, quad = lane >> 4;
  const short* kb = Kh + (size_t)bh * 128 * 32;
  const short* vb = Vh + (size_t)bh * 128 * 32;
  const short* qb = Qh + ((size_t)bh * OBS + q0) * 32;

  for (int i = tid * 8; i < 128 * 32; i += 2048) {
    int r = i >> 5, c = i & 31;
    *(int4*)&Kl[r * 40 + c] = *(const int4*)&kb[i];
  }
  for (int i = tid * 8; i < 64 * 32; i += 2048) {
    int r = i >> 5, c = i & 31;
    *(int4*)&Ql[r * 40 + c] = *(const int4*)&qb[i];
  }
  for (int i = tid * 8; i < 128 * 32; i += 2048) {
    int r = i >> 5, c = i & 31;
    int4 vv4 = *(const int4*)&vb[i];
    short* vv = (short*)&vv4;
#pragma unroll
    for (int j = 0; j < 8; j++) Vt[(c + j) * 136 + r] = vv[j];
  }
  __syncthreads();

  const float scale = 0.08838834764831845f;  // 1/sqrt(128)
  bf16x8 afrag = *(bf16x8*)&Ql[(wv * 16 + lm) * 40 + quad * 8];
#pragma unroll
  for (int nt = 0; nt < 8; nt++) {
    bf16x8 bfrag = *(bf16x8*)&Kl[(nt * 16 + lm) * 40 + quad * 8];
    floatx4 c = {0.f, 0.f, 0.f, 0.f};
    c = __builtin_amdgcn_mfma_f32_16x16x32_bf16(afrag, bfrag, c, 0, 0, 0);
#pragma unroll
    for (int r = 0; r < 4; r++)
      Sl[(wv * 16 + quad * 4 + r) * 132 + nt * 16 + lm] = c[r] * scale;
  }

  {
    int row = tid >> 2, qtr = tid & 3;
    float* srow = &Sl[row * 132 + qtr * 32];
    floatx4 sv[8];
    float mx = -1e30f;
#pragma unroll
    for (int i = 0; i < 8; i++) {
      floatx4 v = *(floatx4*)&srow[i * 4];
      sv[i] = v;
      mx = fmaxf(mx, fmaxf(fmaxf(v[0], v[1]), fmaxf(v[2], v[3])));
    }
    mx = fmaxf(mx, __shfl_xor(mx, 1));
    mx = fmaxf(mx, __shfl_xor(mx, 2));
    float sum = 0.f;
#pragma unroll
    for (int i = 0; i < 8; i++) {
      floatx4 v = sv[i];
      float e0 = __expf(v[0] - mx), e1 = __expf(v[1] - mx);
      float e2 = __expf(v[2] - mx), e3 = __expf(v[3] - mx);
      sum += (e0 + e1) + (e2 + e3);
      *(short4*)&Pl[row * 136 + qtr * 32 + i * 4] =
          make_short4(f2bf(e0), f2bf(e1), f2bf(e2), f2bf(e3));
    }
    sum += __shfl_xor(sum, 1);
    sum += __shfl_xor(sum, 2);
    if (qtr == 0) linv[row] = 1.f / sum;
  }

  floatx4 oacc[2] = {{0.f, 0.f, 0.f, 0.f}, {0.f, 0.f, 0.f, 0.f}};
#pragma unroll
  for (int kc = 0; kc < 4; kc++) {
    bf16x8 pf = *(bf16x8*)&Pl[(wv * 16 + lm) * 136 + kc * 32 + quad * 8];
#pragma unroll
    for (int nt2 = 0; nt2 < 2; nt2++) {
      bf16x8 vf = *(bf16x8*)&Vt[(nt2 * 16 + lm) * 136 + kc * 32 + quad * 8];
      oacc[nt2] = __builtin_amdgcn_mfma_f32_16x16x32_bf16(pf, vf, oacc[nt2], 0, 0, 0);
    }
  }
  short* Ol = (short*)Sl;
#pragma unroll
  for (int nt2 = 0; nt2 < 2; nt2++) {
#pragma unroll
    for (int r = 0; r < 4; r++) {
      int qrow = wv * 16 + quad * 4 + r;
      float li = linv[qrow];
      float q = bf2f(Ql[qrow * 40 + nt2 * 16 + lm]);
      Ol[qrow * 136 + nt2 * 16 + lm] = f2bf(q + oacc[nt2][r] * li);
    }
  }
  __syncthreads();
  {
    int rr = tid >> 2, seg = tid & 3;
    size_t o = ((size_t)b * OBS + q0 + rr) * 128 + h * 32 + seg * 32;
    // note: output col block = h*32? NO — output is full 128 row, segs cover it
    o = ((size_t)b * OBS + q0 + rr) * 128 + seg * 32;
    (void)h;
    // only head h's columns are computed by this block; write head slice only
  }
  // head-sliced coalesced write: 64 rows x 32 cols (this head)
  {
    int rr = tid >> 2, seg = tid & 3;   // seg indexes 8-short chunks of 32 cols
    size_t o = ((size_t)b * OBS + q0 + rr) * 128 + h * 32 + seg * 8;
    *(int4*)&O[o] = *(int4*)&Ol[rr * 136 + seg * 8];
  }
}

// ---------------------------------------------------------------------------
// Kernel 4b: MAB1 attention (bf16 in), flash over 8 key splits.
// ---------------------------------------------------------------------------
__global__ __launch_bounds__(256) void attn1_kernel(
    const short* __restrict__ Qh,   // (NH,128,32) bf16
    const short* __restrict__ Kh,   // (64,4096,32) bf16
    const short* __restrict__ Vh,
    const float* __restrict__ mk,
    float* __restrict__ Opart, float* __restrict__ mpart,
    float* __restrict__ lpart) {
  __shared__ __align__(16) short Ql[128 * 40];
  __shared__ __align__(16) short Kc[64 * 40];
  __shared__ __align__(16) short Vtc[32 * 72];
  __shared__ __align__(16) short Pl[128 * 72];
  __shared__ float mkc[64];
  int bh = blockIdx.x;
  int b = bh >> 2, h = bh & 3;
  int ks = blockIdx.y;
  int tid = threadIdx.x;
  int wv = tid >> 6, lane = tid & 63, lm = lane & 15, quad = lane >> 4;

  const short* qbg = Qh + (size_t)h * 128 * 32;
  for (int i = tid * 8; i < 128 * 32; i += 2048) {
    int r = i >> 5, c = i & 31;
    *(int4*)&Ql[r * 40 + c] = *(const int4*)&qbg[i];
  }
  __syncthreads();
  bf16x8 aq[2];
  aq[0] = *(bf16x8*)&Ql[(wv * 32 + lm) * 40 + quad * 8];
  aq[1] = *(bf16x8*)&Ql[(wv * 32 + 16 + lm) * 40 + quad * 8];

  float m_i[2][4], l_i[2][4];
  floatx4 oacc[2][2];
#pragma unroll
  for (int mt = 0; mt < 2; mt++) {
#pragma unroll
    for (int r = 0; r < 4; r++) { m_i[mt][r] = -1e30f; l_i[mt][r] = 0.f; }
    oacc[mt][0] = (floatx4){0.f, 0.f, 0.f, 0.f};
    oacc[mt][1] = (floatx4){0.f, 0.f, 0.f, 0.f};
  }
  const float scale = 0.08838834764831845f;
  const short* kbase = Kh + ((size_t)bh * OBS + ks * 512) * 32;
  const short* vbase = Vh + ((size_t)bh * OBS + ks * 512) * 32;
  const float* mkb = mk + (size_t)b * OBS + ks * 512;

  for (int ch = 0; ch < 8; ch++) {
    __syncthreads();
    {
      int i = tid * 8;   // covers 64*32 = 2048 shorts exactly
      int r = i >> 5, c = i & 31;
      *(int4*)&Kc[r * 40 + c] = *(const int4*)&kbase[ch * 2048 + i];
      int4 vv4 = *(const int4*)&vbase[ch * 2048 + i];
      short* vv = (short*)&vv4;
#pragma unroll
      for (int j = 0; j < 8; j++) Vtc[(c + j) * 72 + r] = vv[j];
    }
    if (tid < 64) mkc[tid] = mkb[ch * 64 + tid];
    __syncthreads();

    floatx4 sf[2][4];
#pragma unroll
    for (int nt = 0; nt < 4; nt++) {
      bf16x8 bfrag = *(bf16x8*)&Kc[(nt * 16 + lm) * 40 + quad * 8];
      floatx4 z = {0.f, 0.f, 0.f, 0.f};
      sf[0][nt] = __builtin_amdgcn_mfma_f32_16x16x32_bf16(aq[0], bfrag, z, 0, 0, 0);
      sf[1][nt] = __builtin_amdgcn_mfma_f32_16x16x32_bf16(aq[1], bfrag, z, 0, 0, 0);
    }
#pragma unroll
    for (int nt = 0; nt < 4; nt++) {
      float mkv = mkc[nt * 16 + lm];
      bool ok = mkv > 0.f;
#pragma unroll
      for (int mt = 0; mt < 2; mt++)
#pragma unroll
        for (int r = 0; r < 4; r++)
          sf[mt][nt][r] = ok ? sf[mt][nt][r] * scale : -1e10f;
    }
#pragma unroll
    for (int mt = 0; mt < 2; mt++) {
#pragma unroll
      for (int r = 0; r < 4; r++) {
        float mx = fmaxf(fmaxf(sf[mt][0][r], sf[mt][1][r]),
                         fmaxf(sf[mt][2][r], sf[mt][3][r]));
        mx = fmaxf(mx, __shfl_xor(mx, 1));
        mx = fmaxf(mx, __shfl_xor(mx, 2));
        mx = fmaxf(mx, __shfl_xor(mx, 4));
        mx = fmaxf(mx, __shfl_xor(mx, 8));
        float mn = fmaxf(m_i[mt][r], mx);
        float al = __expf(m_i[mt][r] - mn);
        float ps = 0.f;
#pragma unroll
        for (int nt = 0; nt < 4; nt++) {
          float p = __expf(sf[mt][nt][r] - mn);
          sf[mt][nt][r] = p;
          ps += p;
        }
        ps += __shfl_xor(ps, 1);
        ps += __shfl_xor(ps, 2);
        ps += __shfl_xor(ps, 4);
        ps += __shfl_xor(ps, 8);
        l_i[mt][r] = l_i[mt][r] * al + ps;
        m_i[mt][r] = mn;
        oacc[mt][0] *= al;
        oacc[mt][1] *= al;
      }
    }
#pragma unroll
    for (int mt = 0; mt < 2; mt++)
#pragma unroll
      for (int nt = 0; nt < 4; nt++)
#pragma unroll
        for (int r = 0; r < 4; r++)
          Pl[(wv * 32 + mt * 16 + quad * 4 + r) * 72 + nt * 16 + lm] =
              f2bf(sf[mt][nt][r]);
#pragma unroll
    for (int kc = 0; kc < 2; kc++) {
      bf16x8 vf0 = *(bf16x8*)&Vtc[lm * 72 + kc * 32 + quad * 8];
      bf16x8 vf1 = *(bf16x8*)&Vtc[(16 + lm) * 72 + kc * 32 + quad * 8];
#pragma unroll
      for (int mt = 0; mt < 2; mt++) {
        bf16x8 pf = *(bf16x8*)&Pl[(wv * 32 + mt * 16 + lm) * 72 + kc * 32 + quad * 8];
        oacc[mt][0] = __builtin_amdgcn_mfma_f32_16x16x32_bf16(pf, vf0, oacc[mt][0], 0, 0, 0);
        oacc[mt][1] = __builtin_amdgcn_mfma_f32_16x16x32_bf16(pf, vf1, oacc[mt][1], 0, 0, 0);
      }
    }
  }
  float* ob = Opart + (size_t)(ks * 64 + bh) * 128 * 32;
#pragma unroll
  for (int mt = 0; mt < 2; mt++) {
#pragma unroll
    for (int r = 0; r < 4; r++) {
      int row = wv * 32 + mt * 16 + quad * 4 + r;
      ob[(size_t)row * 32 + lm] = oacc[mt][0][r];
      ob[(size_t)row * 32 + 16 + lm] = oacc[mt][1][r];
      if (lm == 0) {
        mpart[(size_t)(ks * 64 + bh) * 128 + row] = m_i[mt][r];
        lpart[(size_t)(ks * 64 + bh) * 128 + row] = l_i[mt][r];
      }
    }
  }
}

// combine 8 key-split partials -> O bf16 (B,128,128) with Q residual
__global__ __launch_bounds__(256) void attn1_combine_kernel(
    const float* __restrict__ Opart, const float* __restrict__ mpart,
    const float* __restrict__ lpart, const short* __restrict__ Qh,
    short* __restrict__ O) {
  int bh = blockIdx.x;
  int b = bh >> 2, h = bh & 3;
  int q = blockIdx.y * 8 + (threadIdx.x >> 5);
  int d = threadIdx.x & 31;
  float mv[8], lv[8], m = -1e30f;
#pragma unroll
  for (int s = 0; s < 8; s++) {
    mv[s] = mpart[(size_t)(s * 64 + bh) * 128 + q];
    lv[s] = lpart[(size_t)(s * 64 + bh) * 128 + q];
    m = fmaxf(m, mv[s]);
  }
  float l = 0.f, o = 0.f;
#pragma unroll
  for (int s = 0; s < 8; s++) {
    float w = __expf(mv[s] - m);
    l += lv[s] * w;
    o += Opart[((size_t)(s * 64 + bh) * 128 + q) * 32 + d] * w;
  }
  float qv = bf2f(Qh[((size_t)h * 128 + q) * 32 + d]);
  O[((size_t)b * 128 + q) * 128 + h * 32 + d] = f2bf(qv + o / l);
}

// ---------------------------------------------------------------------------
// Kernel 5: MFMA fc_o + epilogue. O bf16 rows. mode0: Zout=O+relu (fp32)
// mode1: Zout = Zin + (O+relu)*mk
// ---------------------------------------------------------------------------
__global__ __launch_bounds__(256) void mfma_fco_kernel(
    const short* __restrict__ O, const short* __restrict__ Wt,
    const float* __restrict__ bias, const float* __restrict__ mk,
    const float* __restrict__ Zin, float* __restrict__ Zout, int mode) {
  __shared__ __align__(16) short Xl[64 * 136];
  __shared__ __align__(16) short Wl[128 * 136];
  int tid = threadIdx.x;
  int rb = blockIdx.x * 64;
  for (int i = tid * 8; i < 64 * 128; i += 2048) {
    int rr = i >> 7, c = i & 127;
    *(int4*)&Xl[rr * 136 + c] = *(const int4*)&O[(size_t)(rb + rr) * 128 + c];
  }
  for (int i = tid * 8; i < 128 * 128; i += 2048)
    *(int4*)&Wl[(i >> 7) * 136 + (i & 127)] = *(const int4*)&Wt[i];
  __syncthreads();
  int wv = tid >> 6, lane = tid & 63, lm = lane & 15, quad = lane >> 4;
  bf16x8 af[4];
#pragma unroll
  for (int kc = 0; kc < 4; kc++)
    af[kc] = *(bf16x8*)&Xl[(wv * 16 + lm) * 136 + kc * 32 + quad * 8];
  floatx4 acc[8];
#pragma unroll
  for (int nt = 0; nt < 8; nt++) acc[nt] = (floatx4){0.f, 0.f, 0.f, 0.f};
#pragma unroll
  for (int kc = 0; kc < 4; kc++) {
    bf16x8 a = af[kc];
#pragma unroll
    for (int nt = 0; nt < 8; nt++) {
      bf16x8 bfr = *(bf16x8*)&Wl[(nt * 16 + lm) * 136 + kc * 32 + quad * 8];
      acc[nt] = __builtin_amdgcn_mfma_f32_16x16x32_bf16(a, bfr, acc[nt], 0, 0, 0);
    }
  }
  __syncthreads();
  float* Fl = (float*)Wl;   // [64][132]
#pragma unroll
  for (int nt = 0; nt < 8; nt++) {
    int col = nt * 16 + lm;
    float bn = bias[col];
#pragma unroll
    for (int r = 0; r < 4; r++) {
      int row = wv * 16 + quad * 4 + r;
      float ov = bf2f(Xl[row * 136 + col]);
      Fl[row * 132 + col] = ov + fmaxf(acc[nt][r] + bn, 0.f);
    }
  }
  __syncthreads();
  int rr = tid >> 2, seg = tid & 3;
  int r = rb + rr;
  if (mode) {
    float mkv = mk[r];
#pragma unroll
    for (int j = 0; j < 8; j++) {
      float4 f = *(float4*)&Fl[rr * 132 + seg * 32 + j * 4];
      float4 z = *(const float4*)&Zin[(size_t)r * 128 + seg * 32 + j * 4];
      z.x += f.x * mkv; z.y += f.y * mkv; z.z += f.z * mkv; z.w += f.w * mkv;
      *(float4*)&Zout[(size_t)r * 128 + seg * 32 + j * 4] = z;
    }
  } else {
#pragma unroll
    for (int j = 0; j < 8; j++) {
      float4 f = *(float4*)&Fl[rr * 132 + seg * 32 + j * 4];
      *(float4*)&Zout[(size_t)r * 128 + seg * 32 + j * 4] = f;
    }
  }
}

// ---------------------------------------------------------------------------
extern "C" void kernel_launch(void* const* d_in, const int* in_sizes, int n_in,
                              void* d_out, int out_size, void* d_ws,
                              size_t ws_size, hipStream_t stream) {
  const float* cx    = (const float*)d_in[0];
  const float* value = (const float*)d_in[1];
  const float* mask  = (const float*)d_in[2];
  const float* iff_w = (const float*)d_in[4];
  const float* iff_b = (const float*)d_in[5];
  const float* indp  = (const float*)d_in[6];
  const float* q0w = (const float*)d_in[7];  const float* q0b = (const float*)d_in[8];
  const float* k0w = (const float*)d_in[9];  const float* k0b = (const float*)d_in[10];
  const float* v0w = (const float*)d_in[11]; const float* v0b = (const float*)d_in[12];
  const float* o0w = (const float*)d_in[13]; const float* o0b = (const float*)d_in[14];
  const float* q1w = (const float*)d_in[15]; const float* q1b = (const float*)d_in[16];
  const float* k1w = (const float*)d_in[17]; const float* k1b = (const float*)d_in[18];
  const float* v1w = (const float*)d_in[19]; const float* v1b = (const float*)d_in[20];
  const float* o1w = (const float*)d_in[21]; const float* o1b = (const float*)d_in[22];

  char* ws = (char*)d_ws;
  short* Wt    = (short*)ws;  ws += (size_t)24 * 16384 * 2;
  int*   order = (int*)ws;    ws += (size_t)NBATCH * OBS * 4;
  float* mk_g  = (float*)ws;  ws += (size_t)NBATCH * OBS * 4;
  float* Z     = (float*)ws;  ws += (size_t)NBATCH * OBS * DK * 4;
  short* Qb    = (short*)ws;  ws += (size_t)NBATCH * OBS * DK * 2;
  short* Kb    = (short*)ws;  ws += (size_t)NBATCH * OBS * DK * 2;
  short* Vb    = (short*)ws;  ws += (size_t)NBATCH * OBS * DK * 2;
  short* Ob    = (short*)ws;  ws += (size_t)NBATCH * OBS * DK * 2;
  short* qh_b  = (short*)ws;  ws += (size_t)NH * 128 * DH * 2;
  short* khb   = (short*)ws;  ws += (size_t)NBATCH * NH * 128 * DH * 2;
  short* vhb   = (short*)ws;  ws += (size_t)NBATCH * NH * 128 * DH * 2;
  short* o_sb  = (short*)ws;  ws += (size_t)NBATCH * 128 * DK * 2;
  float* Hbuf  = (float*)ws;  ws += (size_t)NBATCH * 128 * DK * 4;
  float* Opart = (float*)ws;  ws += (size_t)8 * 64 * 128 * 32 * 4;
  float* mpart = (float*)ws;  ws += (size_t)8 * 64 * 128 * 4;
  float* lpart = (float*)ws;  ws += (size_t)8 * 64 * 128 * 4;

  float* outZ  = (float*)d_out;
  float* outMk = outZ + (size_t)NBATCH * OBS * DK;

  prep_weights_kernel<<<24, 256, 0, stream>>>(q0w, k0w, v0w, o0w, q1w, k1w,
                                              v1w, o1w, Wt);
  build_order_kernel<<<NBATCH, 1024, 0, stream>>>(mask, order, mk_g, outMk);
  embed_kernel<<<NBATCH * OBS, 128, 0, stream>>>(order, mk_g, cx, value, iff_w,
                                                 iff_b, Z);

  for (int i = 0; i < 3; i++) {
    const size_t bo = (size_t)i * DK;
    const short* Wl0 = Wt + (size_t)i * 8 * 16384;
    const short* Wq0 = Wl0 + 0 * 16384, *Wk0 = Wl0 + 1 * 16384;
    const short* Wv0 = Wl0 + 2 * 16384, *Wo0 = Wl0 + 3 * 16384;
    const short* Wq1 = Wl0 + 4 * 16384, *Wk1 = Wl0 + 5 * 16384;
    const short* Wv1 = Wl0 + 6 * 16384, *Wo1 = Wl0 + 7 * 16384;
    // ---- MAB1: H = MAB(I, Z), key-masked ----
    mfma_proj_kernel<<<2, 256, 0, stream>>>(indp + (size_t)i * 128 * DK, Wq0,
                                            q0b + bo, qh_b, nullptr, nullptr,
                                            nullptr, 7);
    mfma_proj_kernel<<<1024, 256, 0, stream>>>(Z, Wk0, k0b + bo, Kb, Wv0,
                                               v0b + bo, Vb, 12);
    attn1_kernel<<<dim3(NBATCH * NH, 8), 256, 0, stream>>>(
        qh_b, Kb, Vb, mk_g, Opart, mpart, lpart);
    attn1_combine_kernel<<<dim3(NBATCH * NH, 16), 256, 0, stream>>>(
        Opart, mpart, lpart, qh_b, o_sb);
    mfma_fco_kernel<<<32, 256, 0, stream>>>(o_sb, Wo0, o0b + bo, nullptr,
                                            nullptr, Hbuf, 0);
    // ---- MAB2: Zn = MAB(Z, H); Z += Zn*mk ----
    mfma_proj_kernel<<<1024, 256, 0, stream>>>(Z, Wq1, q1b + bo, Qb, nullptr,
                                               nullptr, nullptr, 12);
    mfma_proj_kernel<<<32, 256, 0, stream>>>(Hbuf, Wk1, k1b + bo, khb, Wv1,
                                             v1b + bo, vhb, 7);
    attn2_kernel<<<dim3(NBATCH * NH, OBS / 64), 256, 0, stream>>>(Qb, khb, vhb,
                                                                  Ob);
    mfma_fco_kernel<<<1024, 256, 0, stream>>>(Ob, Wo1, o1b + bo, mk_g, Z,
                                              (i < 2) ? Z : outZ, 1);
  }
}

// Round 4
// 530.815 us; speedup vs baseline: 6.5085x; 1.1750x over previous
//
#include <hip/hip_runtime.h>
#include <math.h>

#define NBATCH 16
#define SEQL   512
#define DIM    41
#define LDFLAT (SEQL*DIM)   // 20992
#define OBS    4096
#define DK     128
#define NH     4
#define DH     32

typedef short bf16x8 __attribute__((ext_vector_type(8)));
typedef short short8v __attribute__((ext_vector_type(8)));
typedef float floatx4 __attribute__((ext_vector_type(4)));

__device__ __forceinline__ short f2bf(float f) {
  union { float f; unsigned u; } v;
  v.f = f;
  unsigned r = (v.u + 0x7fffu + ((v.u >> 16) & 1u)) >> 16;
  return (short)r;
}
__device__ __forceinline__ float bf2f(short s) {
  union { unsigned u; float f; } v;
  v.u = ((unsigned)(unsigned short)s) << 16;
  return v.f;
}

// ---- shared GEMM building blocks (64 rows x 128 cols, K=128) ----
__device__ __forceinline__ void stage_w(short* Wl, const short* __restrict__ Wt,
                                        int tid) {
#pragma unroll
  for (int i = tid * 8; i < 128 * 128; i += 2048)
    *(int4*)&Wl[(i >> 7) * 136 + (i & 127)] = *(const int4*)&Wt[i];
}
__device__ __forceinline__ void load_af(const short* Xl, int wv, int lm,
                                        int quad, bf16x8 af[4]) {
#pragma unroll
  for (int kc = 0; kc < 4; kc++)
    af[kc] = *(bf16x8*)&Xl[(wv * 16 + lm) * 136 + kc * 32 + quad * 8];
}
__device__ __forceinline__ void gemm8(const short* Wl, const bf16x8 af[4],
                                      int lm, int quad, floatx4 acc[8]) {
#pragma unroll
  for (int nt = 0; nt < 8; nt++) acc[nt] = (floatx4){0.f, 0.f, 0.f, 0.f};
#pragma unroll
  for (int kc = 0; kc < 4; kc++) {
    bf16x8 a = af[kc];
#pragma unroll
    for (int nt = 0; nt < 8; nt++) {
      bf16x8 b = *(bf16x8*)&Wl[(nt * 16 + lm) * 136 + kc * 32 + quad * 8];
      acc[nt] = __builtin_amdgcn_mfma_f32_16x16x32_bf16(a, b, acc[nt], 0, 0, 0);
    }
  }
}
__device__ __forceinline__ void store_sl(short* Sl, const floatx4 acc[8],
                                         const float* __restrict__ bias,
                                         int wv, int lm, int quad) {
#pragma unroll
  for (int nt = 0; nt < 8; nt++) {
    int col = nt * 16 + lm;
    float bn = bias[col];
#pragma unroll
    for (int r = 0; r < 4; r++)
      Sl[(wv * 16 + quad * 4 + r) * 136 + col] = f2bf(acc[nt][r] + bn);
  }
}
// write Sl rows rb..rb+63 to head-split out[((b*NH+h)*N+n)*32+d], N=1<<nshift
__device__ __forceinline__ void write_hs(const short* Sl,
                                         short* __restrict__ out, int rb,
                                         int nshift, int tid) {
  int rr = tid >> 2, hh = tid & 3;
  int r = rb + rr;
  int bb = r >> nshift, nn = r & ((1 << nshift) - 1);
  size_t o = (((size_t)(bb * NH + hh) << nshift) + nn) * 32;
#pragma unroll
  for (int j = 0; j < 4; j++)
    *(int4*)&out[o + j * 8] = *(int4*)&Sl[rr * 136 + hh * 32 + j * 8];
}

// ---------------------------------------------------------------------------
// Kernel: weights -> bf16 transposed Wt[n][k]. grid 24 (= layer*8+wi)
// ---------------------------------------------------------------------------
__global__ __launch_bounds__(256) void prep_weights_kernel(
    const float* __restrict__ q0w, const float* __restrict__ k0w,
    const float* __restrict__ v0w, const float* __restrict__ o0w,
    const float* __restrict__ q1w, const float* __restrict__ k1w,
    const float* __restrict__ v1w, const float* __restrict__ o1w,
    short* __restrict__ Wt) {
  __shared__ float Tl[128 * 132];
  int id = blockIdx.x, l = id >> 3, wi = id & 7;
  const float* s;
  switch (wi) {
    case 0: s = q0w; break; case 1: s = k0w; break;
    case 2: s = v0w; break; case 3: s = o0w; break;
    case 4: s = q1w; break; case 5: s = k1w; break;
    case 6: s = v1w; break; default: s = o1w; break;
  }
  s += (size_t)l * 16384;
  int tid = threadIdx.x;
  for (int i = tid * 4; i < 16384; i += 1024) {
    int k = i >> 7, n = i & 127;
    float4 x = *(const float4*)&s[i];
    Tl[k * 132 + n + 0] = x.x; Tl[k * 132 + n + 1] = x.y;
    Tl[k * 132 + n + 2] = x.z; Tl[k * 132 + n + 3] = x.w;
  }
  __syncthreads();
  short* dst = Wt + (size_t)id * 16384;
  int n = tid >> 1, k0 = (tid & 1) * 64;
  for (int jc = 0; jc < 8; jc++) {
    short8v t;
#pragma unroll
    for (int j = 0; j < 8; j++) t[j] = f2bf(Tl[(k0 + jc * 8 + j) * 132 + n]);
    *(short8v*)&dst[n * 128 + k0 + jc * 8] = t;
  }
}

// ---------------------------------------------------------------------------
// Kernel: stable order + gathered mask (writes mk to ws and d_out tail)
// ---------------------------------------------------------------------------
__global__ __launch_bounds__(1024) void build_order_kernel(
    const float* __restrict__ mask, int* __restrict__ order,
    float* __restrict__ mk_out, float* __restrict__ mk_out2) {
  int b = blockIdx.x;
  const float* m = mask + (size_t)b * LDFLAT;
  int tid = threadIdx.x;
  int lane = tid & 63, w = tid >> 6;
  __shared__ int wsums[16];
  __shared__ int s_total_ones;
  __shared__ int s_chunk_ones;
  __shared__ int s_ones_base;
  __shared__ int s_zeros_base;

  int cnt = 0;
  for (int j = tid; j < LDFLAT; j += 1024) cnt += (m[j] > 0.f) ? 1 : 0;
  for (int off = 32; off > 0; off >>= 1) cnt += __shfl_xor(cnt, off);
  if (lane == 0) wsums[w] = cnt;
  __syncthreads();
  if (tid == 0) {
    int t = 0;
    for (int i = 0; i < 16; i++) t += wsums[i];
    s_total_ones = t; s_ones_base = 0; s_zeros_base = 0;
  }
  __syncthreads();
  int total_ones = s_total_ones;

  for (int c0 = 0; c0 < LDFLAT; c0 += 1024) {
    __syncthreads();
    int j = c0 + tid;
    bool valid = (j < LDFLAT);
    float mv = valid ? m[j] : 0.f;
    int one = (valid && mv > 0.f) ? 1 : 0;
    int v = one;
    for (int off = 1; off < 64; off <<= 1) {
      int t = __shfl_up(v, (unsigned)off);
      if (lane >= off) v += t;
    }
    if (lane == 63) wsums[w] = v;
    __syncthreads();
    if (tid == 0) {
      int run = 0;
      for (int i = 0; i < 16; i++) { int t = wsums[i]; wsums[i] = run; run += t; }
      s_chunk_ones = run;
    }
    __syncthreads();
    int ones_before = (v - one) + wsums[w];
    int ob = s_ones_base, zb = s_zeros_base, chunk_ones = s_chunk_ones;
    int rem = LDFLAT - c0;
    int chunk_valid = rem < 1024 ? rem : 1024;
    int valid_before = tid < rem ? tid : rem;
    if (valid) {
      int pos = one ? (ob + ones_before)
                    : (total_ones + zb + (valid_before - ones_before));
      if (pos < OBS) {
        order[b * OBS + pos] = j;
        mk_out[b * OBS + pos] = mv;
        mk_out2[b * OBS + pos] = mv;
      }
    }
    __syncthreads();
    if (tid == 0) {
      s_ones_base = ob + chunk_ones;
      s_zeros_base = zb + (chunk_valid - chunk_ones);
    }
  }
}

// ---------------------------------------------------------------------------
// Kernel: ind-point Q projections, all 3 layers. grid (2, 3)
// ---------------------------------------------------------------------------
__global__ __launch_bounds__(256) void qh_proj_kernel(
    const float* __restrict__ indp, const short* __restrict__ Wt,
    const float* __restrict__ q0b, short* __restrict__ qh_b) {
  __shared__ __align__(16) short Xl[64 * 136];
  __shared__ __align__(16) short Wl[128 * 136];
  int l = blockIdx.y, rb = blockIdx.x * 64;
  const float* X = indp + (size_t)l * 16384 + (size_t)rb * 128;
  const short* W = Wt + (size_t)(l * 8) * 16384;
  const float* bias = q0b + (size_t)l * 128;
  short* out = qh_b + (size_t)l * 16384;
  int tid = threadIdx.x;
  for (int i = tid * 4; i < 64 * 128; i += 1024) {
    int rr = i >> 7, c = i & 127;
    float4 x = *(const float4*)&X[i];
    *(short4*)&Xl[rr * 136 + c] =
        make_short4(f2bf(x.x), f2bf(x.y), f2bf(x.z), f2bf(x.w));
  }
  stage_w(Wl, W, tid);
  __syncthreads();
  int wv = tid >> 6, lane = tid & 63, lm = lane & 15, quad = lane >> 4;
  bf16x8 af[4];
  load_af(Xl, wv, lm, quad, af);
  floatx4 acc[8];
  gemm8(Wl, af, lm, quad, acc);
  __syncthreads();
  store_sl(Wl, acc, bias, wv, lm, quad);
  __syncthreads();
  write_hs(Wl, out, rb, 7, tid);
}

// ---------------------------------------------------------------------------
// Kernel: fusedA — embed (layer-0 Z) + K0/V0 + Q1 projections. grid 1024.
// ---------------------------------------------------------------------------
__global__ __launch_bounds__(256) void fusedA_kernel(
    const int* __restrict__ order, const float* __restrict__ mk_g,
    const float* __restrict__ cx, const float* __restrict__ value,
    const float* __restrict__ iff_w, const float* __restrict__ iff_b,
    float* __restrict__ Z,
    const short* __restrict__ Wk, const float* __restrict__ kbias,
    short* __restrict__ Kb,
    const short* __restrict__ Wv, const float* __restrict__ vbias,
    short* __restrict__ Vb,
    const short* __restrict__ Wq, const float* __restrict__ qbias,
    short* __restrict__ Qb) {
  __shared__ __align__(16) short Xl[64 * 136];
  __shared__ __align__(16) short Wl[128 * 136];
  __shared__ int   rdd[64];
  __shared__ float rdt[64], rdu[64], rdm[64];
  int tid = threadIdx.x;
  int rb = blockIdx.x * 64;
  if (tid < 64) {
    int idx = rb + tid;
    int b = idx >> 12;
    int j = order[idx];
    int l = j / DIM;
    rdd[tid] = j - l * DIM;
    rdt[tid] = cx[b * SEQL + l];
    rdu[tid] = value[(size_t)b * LDFLAT + j];
    rdm[tid] = mk_g[idx];
  }
  stage_w(Wl, Wk, tid);
  __syncthreads();
  for (int i = tid; i < 64 * 128; i += 256) {
    int rr = i >> 7, k = i & 127;
    float y = iff_w[rdd[rr] * DK + k] + rdt[rr] * iff_w[41 * DK + k] +
              rdu[rr] * iff_w[42 * DK + k] + iff_b[k];
    float z = fmaxf(y, 0.f) * rdm[rr];
    Z[(size_t)(rb + rr) * DK + k] = z;
    Xl[rr * 136 + k] = f2bf(z);
  }
  __syncthreads();
  int wv = tid >> 6, lane = tid & 63, lm = lane & 15, quad = lane >> 4;
  bf16x8 af[4];
  load_af(Xl, wv, lm, quad, af);
  floatx4 acc[8];
  gemm8(Wl, af, lm, quad, acc);
  __syncthreads();
  store_sl(Wl, acc, kbias, wv, lm, quad);
  __syncthreads();
  write_hs(Wl, Kb, rb, 12, tid);
  __syncthreads();
  stage_w(Wl, Wv, tid);
  __syncthreads();
  gemm8(Wl, af, lm, quad, acc);
  __syncthreads();
  store_sl(Wl, acc, vbias, wv, lm, quad);
  __syncthreads();
  write_hs(Wl, Vb, rb, 12, tid);
  __syncthreads();
  stage_w(Wl, Wq, tid);
  __syncthreads();
  gemm8(Wl, af, lm, quad, acc);
  __syncthreads();
  store_sl(Wl, acc, qbias, wv, lm, quad);
  __syncthreads();
  write_hs(Wl, Qb, rb, 12, tid);
}

// ---------------------------------------------------------------------------
// Kernel: MAB1 attention (bf16), flash over 8 key splits. grid (64, 8).
// ---------------------------------------------------------------------------
__global__ __launch_bounds__(256) void attn1_kernel(
    const short* __restrict__ Qh,   // (NH,128,32) bf16, layer base
    const short* __restrict__ Kh, const short* __restrict__ Vh,
    const float* __restrict__ mk,
    float* __restrict__ Opart, float* __restrict__ mpart,
    float* __restrict__ lpart) {
  __shared__ __align__(16) short Ql[128 * 40];
  __shared__ __align__(16) short Kc[64 * 40];
  __shared__ __align__(16) short Vtc[32 * 72];
  __shared__ __align__(16) short Pl[128 * 72];
  __shared__ float mkc[64];
  int bh = blockIdx.x;
  int b = bh >> 2, h = bh & 3;
  int ks = blockIdx.y;
  int tid = threadIdx.x;
  int wv = tid >> 6, lane = tid & 63, lm = lane & 15, quad = lane >> 4;

  const short* qbg = Qh + (size_t)h * 128 * 32;
  for (int i = tid * 8; i < 128 * 32; i += 2048) {
    int r = i >> 5, c = i & 31;
    *(int4*)&Ql[r * 40 + c] = *(const int4*)&qbg[i];
  }
  __syncthreads();
  bf16x8 aq[2];
  aq[0] = *(bf16x8*)&Ql[(wv * 32 + lm) * 40 + quad * 8];
  aq[1] = *(bf16x8*)&Ql[(wv * 32 + 16 + lm) * 40 + quad * 8];

  float m_i[2][4], l_i[2][4];
  floatx4 oacc[2][2];
#pragma unroll
  for (int mt = 0; mt < 2; mt++) {
#pragma unroll
    for (int r = 0; r < 4; r++) { m_i[mt][r] = -1e30f; l_i[mt][r] = 0.f; }
    oacc[mt][0] = (floatx4){0.f, 0.f, 0.f, 0.f};
    oacc[mt][1] = (floatx4){0.f, 0.f, 0.f, 0.f};
  }
  const float scale = 0.08838834764831845f;
  const short* kbase = Kh + ((size_t)bh * OBS + ks * 512) * 32;
  const short* vbase = Vh + ((size_t)bh * OBS + ks * 512) * 32;
  const float* mkb = mk + (size_t)b * OBS + ks * 512;

  for (int ch = 0; ch < 8; ch++) {
    __syncthreads();
    {
      int i = tid * 8;
      int r = i >> 5, c = i & 31;
      *(int4*)&Kc[r * 40 + c] = *(const int4*)&kbase[ch * 2048 + i];
      int4 vv4 = *(const int4*)&vbase[ch * 2048 + i];
      short* vv = (short*)&vv4;
#pragma unroll
      for (int j = 0; j < 8; j++) Vtc[(c + j) * 72 + r] = vv[j];
    }
    if (tid < 64) mkc[tid] = mkb[ch * 64 + tid];
    __syncthreads();

    floatx4 sf[2][4];
#pragma unroll
    for (int nt = 0; nt < 4; nt++) {
      bf16x8 bfrag = *(bf16x8*)&Kc[(nt * 16 + lm) * 40 + quad * 8];
      floatx4 z = {0.f, 0.f, 0.f, 0.f};
      sf[0][nt] = __builtin_amdgcn_mfma_f32_16x16x32_bf16(aq[0], bfrag, z, 0, 0, 0);
      sf[1][nt] = __builtin_amdgcn_mfma_f32_16x16x32_bf16(aq[1], bfrag, z, 0, 0, 0);
    }
#pragma unroll
    for (int nt = 0; nt < 4; nt++) {
      float mkv = mkc[nt * 16 + lm];
      bool ok = mkv > 0.f;
#pragma unroll
      for (int mt = 0; mt < 2; mt++)
#pragma unroll
        for (int r = 0; r < 4; r++)
          sf[mt][nt][r] = ok ? sf[mt][nt][r] * scale : -1e10f;
    }
#pragma unroll
    for (int mt = 0; mt < 2; mt++) {
#pragma unroll
      for (int r = 0; r < 4; r++) {
        float mx = fmaxf(fmaxf(sf[mt][0][r], sf[mt][1][r]),
                         fmaxf(sf[mt][2][r], sf[mt][3][r]));
        mx = fmaxf(mx, __shfl_xor(mx, 1));
        mx = fmaxf(mx, __shfl_xor(mx, 2));
        mx = fmaxf(mx, __shfl_xor(mx, 4));
        mx = fmaxf(mx, __shfl_xor(mx, 8));
        float mn = fmaxf(m_i[mt][r], mx);
        float al = __expf(m_i[mt][r] - mn);
        float ps = 0.f;
#pragma unroll
        for (int nt = 0; nt < 4; nt++) {
          float p = __expf(sf[mt][nt][r] - mn);
          sf[mt][nt][r] = p;
          ps += p;
        }
        ps += __shfl_xor(ps, 1);
        ps += __shfl_xor(ps, 2);
        ps += __shfl_xor(ps, 4);
        ps += __shfl_xor(ps, 8);
        l_i[mt][r] = l_i[mt][r] * al + ps;
        m_i[mt][r] = mn;
        oacc[mt][0] *= al;
        oacc[mt][1] *= al;
      }
    }
#pragma unroll
    for (int mt = 0; mt < 2; mt++)
#pragma unroll
      for (int nt = 0; nt < 4; nt++)
#pragma unroll
        for (int r = 0; r < 4; r++)
          Pl[(wv * 32 + mt * 16 + quad * 4 + r) * 72 + nt * 16 + lm] =
              f2bf(sf[mt][nt][r]);
#pragma unroll
    for (int kc = 0; kc < 2; kc++) {
      bf16x8 vf0 = *(bf16x8*)&Vtc[lm * 72 + kc * 32 + quad * 8];
      bf16x8 vf1 = *(bf16x8*)&Vtc[(16 + lm) * 72 + kc * 32 + quad * 8];
#pragma unroll
      for (int mt = 0; mt < 2; mt++) {
        bf16x8 pf = *(bf16x8*)&Pl[(wv * 32 + mt * 16 + lm) * 72 + kc * 32 + quad * 8];
        oacc[mt][0] = __builtin_amdgcn_mfma_f32_16x16x32_bf16(pf, vf0, oacc[mt][0], 0, 0, 0);
        oacc[mt][1] = __builtin_amdgcn_mfma_f32_16x16x32_bf16(pf, vf1, oacc[mt][1], 0, 0, 0);
      }
    }
  }
  float* ob = Opart + (size_t)(ks * 64 + bh) * 128 * 32;
#pragma unroll
  for (int mt = 0; mt < 2; mt++) {
#pragma unroll
    for (int r = 0; r < 4; r++) {
      int row = wv * 32 + mt * 16 + quad * 4 + r;
      ob[(size_t)row * 32 + lm] = oacc[mt][0][r];
      ob[(size_t)row * 32 + 16 + lm] = oacc[mt][1][r];
      if (lm == 0) {
        mpart[(size_t)(ks * 64 + bh) * 128 + row] = m_i[mt][r];
        lpart[(size_t)(ks * 64 + bh) * 128 + row] = l_i[mt][r];
      }
    }
  }
}

// ---------------------------------------------------------------------------
// Kernel: fusedB — attn1 combine + fc_o + K1/V1 projections. grid 32.
// ---------------------------------------------------------------------------
__global__ __launch_bounds__(256) void fusedB_kernel(
    const float* __restrict__ Opart, const float* __restrict__ mpart,
    const float* __restrict__ lpart, const short* __restrict__ qh,
    const short* __restrict__ Wo, const float* __restrict__ obias,
    const short* __restrict__ Wk, const float* __restrict__ kbias,
    const short* __restrict__ Wv, const float* __restrict__ vbias,
    short* __restrict__ khb, short* __restrict__ vhb) {
  __shared__ __align__(16) short Xl[64 * 136];
  __shared__ __align__(16) short Wl[128 * 136];
  int tid = threadIdx.x;
  int rb = blockIdx.x * 64;           // row in 2048 = b*128 + n
  int b = rb >> 7, n0 = rb & 127;
  // combine: thread -> (row rr=tid>>2, head hh=tid&3), 32 d each
  {
    int rr = tid >> 2, hh = tid & 3;
    int n = n0 + rr;
    int bh = b * 4 + hh;
    float mv[8], lv[8], m = -1e30f;
#pragma unroll
    for (int s = 0; s < 8; s++) {
      mv[s] = mpart[(size_t)(s * 64 + bh) * 128 + n];
      lv[s] = lpart[(size_t)(s * 64 + bh) * 128 + n];
      m = fmaxf(m, mv[s]);
    }
    float l = 0.f;
    float oa[32];
#pragma unroll
    for (int d = 0; d < 32; d++) oa[d] = 0.f;
#pragma unroll
    for (int s = 0; s < 8; s++) {
      float w = __expf(mv[s] - m);
      l += lv[s] * w;
      const float* op = &Opart[((size_t)(s * 64 + bh) * 128 + n) * 32];
#pragma unroll
      for (int d4 = 0; d4 < 8; d4++) {
        float4 v = *(const float4*)&op[d4 * 4];
        oa[d4 * 4 + 0] += v.x * w; oa[d4 * 4 + 1] += v.y * w;
        oa[d4 * 4 + 2] += v.z * w; oa[d4 * 4 + 3] += v.w * w;
      }
    }
    float li = 1.f / l;
    const short* qp = &qh[((size_t)hh * 128 + n) * 32];
#pragma unroll
    for (int d = 0; d < 32; d++)
      Xl[rr * 136 + hh * 32 + d] = f2bf(bf2f(qp[d]) + oa[d] * li);
  }
  stage_w(Wl, Wo, tid);
  __syncthreads();
  int wv = tid >> 6, lane = tid & 63, lm = lane & 15, quad = lane >> 4;
  bf16x8 af[4];
  load_af(Xl, wv, lm, quad, af);
  floatx4 acc[8];
  gemm8(Wl, af, lm, quad, acc);
  __syncthreads();
  // H = O + relu(acc + bias) -> stage in Wl as bf16
#pragma unroll
  for (int nt = 0; nt < 8; nt++) {
    int col = nt * 16 + lm;
    float bn = obias[col];
#pragma unroll
    for (int r = 0; r < 4; r++) {
      int row = wv * 16 + quad * 4 + r;
      float ov = bf2f(Xl[row * 136 + col]);
      Wl[row * 136 + col] = f2bf(ov + fmaxf(acc[nt][r] + bn, 0.f));
    }
  }
  __syncthreads();
  // copy H into Xl
  for (int i = tid * 8; i < 64 * 128; i += 2048)
    *(int4*)&Xl[(i >> 7) * 136 + (i & 127)] = *(int4*)&Wl[(i >> 7) * 136 + (i & 127)];
  __syncthreads();
  load_af(Xl, wv, lm, quad, af);
  stage_w(Wl, Wk, tid);
  __syncthreads();
  gemm8(Wl, af, lm, quad, acc);
  __syncthreads();
  store_sl(Wl, acc, kbias, wv, lm, quad);
  __syncthreads();
  write_hs(Wl, khb, rb, 7, tid);
  __syncthreads();
  stage_w(Wl, Wv, tid);
  __syncthreads();
  gemm8(Wl, af, lm, quad, acc);
  __syncthreads();
  store_sl(Wl, acc, vbias, wv, lm, quad);
  __syncthreads();
  write_hs(Wl, vhb, rb, 7, tid);
}

// ---------------------------------------------------------------------------
// Kernel: MAB2 attention, register softmax. grid (64, 64). LDS ~42 KB.
// ---------------------------------------------------------------------------
__global__ __launch_bounds__(256) void attn2_kernel(
    const short* __restrict__ Qh, const short* __restrict__ Kh,
    const short* __restrict__ Vh, short* __restrict__ O) {
  __shared__ __align__(16) short Kl[128 * 40];
  __shared__ __align__(16) short Vt[32 * 136];
  __shared__ __align__(16) short Ql[64 * 40];
  __shared__ __align__(16) short Pl[64 * 136];
  int bh = blockIdx.x;
  int b = bh >> 2, h = bh & 3;
  int q0 = blockIdx.y * 64;
  int tid = threadIdx.x;
  int wv = tid >> 6, lane = tid & 63, lm = lane & 15, quad = lane >> 4;
  const short* kb = Kh + (size_t)bh * 128 * 32;
  const short* vb = Vh + (size_t)bh * 128 * 32;
  const short* qb = Qh + ((size_t)bh * OBS + q0) * 32;

  for (int i = tid * 8; i < 128 * 32; i += 2048) {
    int r = i >> 5, c = i & 31;
    *(int4*)&Kl[r * 40 + c] = *(const int4*)&kb[i];
  }
  for (int i = tid * 8; i < 64 * 32; i += 2048) {
    int r = i >> 5, c = i & 31;
    *(int4*)&Ql[r * 40 + c] = *(const int4*)&qb[i];
  }
  for (int i = tid * 8; i < 128 * 32; i += 2048) {
    int r = i >> 5, c = i & 31;
    int4 vv4 = *(const int4*)&vb[i];
    short* vv = (short*)&vv4;
#pragma unroll
    for (int j = 0; j < 8; j++) Vt[(c + j) * 136 + r] = vv[j];
  }
  __syncthreads();

  const float scale = 0.08838834764831845f;
  bf16x8 afrag = *(bf16x8*)&Ql[(wv * 16 + lm) * 40 + quad * 8];
  floatx4 sf[8];
#pragma unroll
  for (int nt = 0; nt < 8; nt++) {
    bf16x8 bfrag = *(bf16x8*)&Kl[(nt * 16 + lm) * 40 + quad * 8];
    floatx4 z = {0.f, 0.f, 0.f, 0.f};
    sf[nt] = __builtin_amdgcn_mfma_f32_16x16x32_bf16(afrag, bfrag, z, 0, 0, 0);
  }
#pragma unroll
  for (int nt = 0; nt < 8; nt++) sf[nt] *= scale;
  float linv[4];
#pragma unroll
  for (int r = 0; r < 4; r++) {
    float mx = sf[0][r];
#pragma unroll
    for (int nt = 1; nt < 8; nt++) mx = fmaxf(mx, sf[nt][r]);
    mx = fmaxf(mx, __shfl_xor(mx, 1));
    mx = fmaxf(mx, __shfl_xor(mx, 2));
    mx = fmaxf(mx, __shfl_xor(mx, 4));
    mx = fmaxf(mx, __shfl_xor(mx, 8));
    float sum = 0.f;
#pragma unroll
    for (int nt = 0; nt < 8; nt++) {
      float p = __expf(sf[nt][r] - mx);
      sf[nt][r] = p;
      sum += p;
    }
    sum += __shfl_xor(sum, 1);
    sum += __shfl_xor(sum, 2);
    sum += __shfl_xor(sum, 4);
    sum += __shfl_xor(sum, 8);
    linv[r] = 1.f / sum;
  }
#pragma unroll
  for (int nt = 0; nt < 8; nt++)
#pragma unroll
    for (int r = 0; r < 4; r++)
      Pl[(wv * 16 + quad * 4 + r) * 136 + nt * 16 + lm] = f2bf(sf[nt][r]);
  __syncthreads();

  floatx4 oacc[2] = {{0.f, 0.f, 0.f, 0.f}, {0.f, 0.f, 0.f, 0.f}};
#pragma unroll
  for (int kc = 0; kc < 4; kc++) {
    bf16x8 pf = *(bf16x8*)&Pl[(wv * 16 + lm) * 136 + kc * 32 + quad * 8];
#pragma unroll
    for (int nt2 = 0; nt2 < 2; nt2++) {
      bf16x8 vf = *(bf16x8*)&Vt[(nt2 * 16 + lm) * 136 + kc * 32 + quad * 8];
      oacc[nt2] = __builtin_amdgcn_mfma_f32_16x16x32_bf16(pf, vf, oacc[nt2], 0, 0, 0);
    }
  }
  __syncthreads();
  short* Ol = Pl;
#pragma unroll
  for (int nt2 = 0; nt2 < 2; nt2++) {
#pragma unroll
    for (int r = 0; r < 4; r++) {
      int qrow = wv * 16 + quad * 4 + r;
      float q = bf2f(Ql[qrow * 40 + nt2 * 16 + lm]);
      Ol[qrow * 136 + nt2 * 16 + lm] = f2bf(q + oacc[nt2][r] * linv[r]);
    }
  }
  __syncthreads();
  int rr = tid >> 2, seg = tid & 3;
  size_t o = ((size_t)b * OBS + q0 + rr) * 128 + h * 32 + seg * 8;
  *(int4*)&O[o] = *(int4*)&Ol[rr * 136 + seg * 8];
}

// ---------------------------------------------------------------------------
// Kernel: fusedC — fc_o + residual Z update + next layer's K0/V0/Q1.
// grid 1024. Wk==null => last layer (no projections).
// ---------------------------------------------------------------------------
__global__ __launch_bounds__(256) void fusedC_kernel(
    const short* __restrict__ Ob, const short* __restrict__ Wo,
    const float* __restrict__ obias, const float* __restrict__ mk,
    const float* __restrict__ Zin, float* __restrict__ Zout,
    const short* __restrict__ Wk, const float* __restrict__ kbias,
    short* __restrict__ Kb,
    const short* __restrict__ Wv, const float* __restrict__ vbias,
    short* __restrict__ Vb,
    const short* __restrict__ Wq, const float* __restrict__ qbias,
    short* __restrict__ Qb) {
  __shared__ __align__(16) short Xl[64 * 136];
  __shared__ __align__(16) short Wl[128 * 136];
  int tid = threadIdx.x;
  int rb = blockIdx.x * 64;
  for (int i = tid * 8; i < 64 * 128; i += 2048) {
    int rr = i >> 7, c = i & 127;
    *(int4*)&Xl[rr * 136 + c] = *(const int4*)&Ob[(size_t)(rb + rr) * 128 + c];
  }
  stage_w(Wl, Wo, tid);
  __syncthreads();
  int wv = tid >> 6, lane = tid & 63, lm = lane & 15, quad = lane >> 4;
  bf16x8 af[4];
  load_af(Xl, wv, lm, quad, af);
  floatx4 acc[8];
  gemm8(Wl, af, lm, quad, acc);
  __syncthreads();
  float* Fl = (float*)Wl;   // 64 x 132 fp32
#pragma unroll
  for (int nt = 0; nt < 8; nt++) {
    int col = nt * 16 + lm;
    float bn = obias[col];
#pragma unroll
    for (int r = 0; r < 4; r++) {
      int row = wv * 16 + quad * 4 + r;
      int gr = rb + row;
      float ov = bf2f(Xl[row * 136 + col]);
      float f = ov + fmaxf(acc[nt][r] + bn, 0.f);
      Fl[row * 132 + col] = Zin[(size_t)gr * 128 + col] + f * mk[gr];
    }
  }
  __syncthreads();
  {
    int rr = tid >> 2, seg = tid & 3;
    int gr = rb + rr;
#pragma unroll
    for (int j = 0; j < 8; j++) {
      float4 f = *(float4*)&Fl[rr * 132 + seg * 32 + j * 4];
      *(float4*)&Zout[(size_t)gr * 128 + seg * 32 + j * 4] = f;
      *(short4*)&Xl[rr * 136 + seg * 32 + j * 4] =
          make_short4(f2bf(f.x), f2bf(f.y), f2bf(f.z), f2bf(f.w));
    }
  }
  if (Wk == nullptr) return;
  __syncthreads();
  load_af(Xl, wv, lm, quad, af);
  stage_w(Wl, Wk, tid);
  __syncthreads();
  gemm8(Wl, af, lm, quad, acc);
  __syncthreads();
  store_sl(Wl, acc, kbias, wv, lm, quad);
  __syncthreads();
  write_hs(Wl, Kb, rb, 12, tid);
  __syncthreads();
  stage_w(Wl, Wv, tid);
  __syncthreads();
  gemm8(Wl, af, lm, quad, acc);
  __syncthreads();
  store_sl(Wl, acc, vbias, wv, lm, quad);
  __syncthreads();
  write_hs(Wl, Vb, rb, 12, tid);
  __syncthreads();
  stage_w(Wl, Wq, tid);
  __syncthreads();
  gemm8(Wl, af, lm, quad, acc);
  __syncthreads();
  store_sl(Wl, acc, qbias, wv, lm, quad);
  __syncthreads();
  write_hs(Wl, Qb, rb, 12, tid);
}

// ---------------------------------------------------------------------------
extern "C" void kernel_launch(void* const* d_in, const int* in_sizes, int n_in,
                              void* d_out, int out_size, void* d_ws,
                              size_t ws_size, hipStream_t stream) {
  const float* cx    = (const float*)d_in[0];
  const float* value = (const float*)d_in[1];
  const float* mask  = (const float*)d_in[2];
  const float* iff_w = (const float*)d_in[4];
  const float* iff_b = (const float*)d_in[5];
  const float* indp  = (const float*)d_in[6];
  const float* q0w = (const float*)d_in[7];  const float* q0b = (const float*)d_in[8];
  const float* k0w = (const float*)d_in[9];  const float* k0b = (const float*)d_in[10];
  const float* v0w = (const float*)d_in[11]; const float* v0b = (const float*)d_in[12];
  const float* o0w = (const float*)d_in[13]; const float* o0b = (const float*)d_in[14];
  const float* q1w = (const float*)d_in[15]; const float* q1b = (const float*)d_in[16];
  const float* k1w = (const float*)d_in[17]; const float* k1b = (const float*)d_in[18];
  const float* v1w = (const float*)d_in[19]; const float* v1b = (const float*)d_in[20];
  const float* o1w = (const float*)d_in[21]; const float* o1b = (const float*)d_in[22];

  char* ws = (char*)d_ws;
  short* Wt    = (short*)ws;  ws += (size_t)24 * 16384 * 2;
  int*   order = (int*)ws;    ws += (size_t)NBATCH * OBS * 4;
  float* mk_g  = (float*)ws;  ws += (size_t)NBATCH * OBS * 4;
  float* Z     = (float*)ws;  ws += (size_t)NBATCH * OBS * DK * 4;
  short* Qb    = (short*)ws;  ws += (size_t)NBATCH * OBS * DK * 2;
  short* Kb    = (short*)ws;  ws += (size_t)NBATCH * OBS * DK * 2;
  short* Vb    = (short*)ws;  ws += (size_t)NBATCH * OBS * DK * 2;
  short* Ob    = (short*)ws;  ws += (size_t)NBATCH * OBS * DK * 2;
  short* qh_b  = (short*)ws;  ws += (size_t)3 * 128 * DK * 2;
  short* khb   = (short*)ws;  ws += (size_t)NBATCH * NH * 128 * DH * 2;
  short* vhb   = (short*)ws;  ws += (size_t)NBATCH * NH * 128 * DH * 2;
  float* Opart = (float*)ws;  ws += (size_t)8 * 64 * 128 * 32 * 4;
  float* mpart = (float*)ws;  ws += (size_t)8 * 64 * 128 * 4;
  float* lpart = (float*)ws;  ws += (size_t)8 * 64 * 128 * 4;

  float* outZ  = (float*)d_out;
  float* outMk = outZ + (size_t)NBATCH * OBS * DK;

  prep_weights_kernel<<<24, 256, 0, stream>>>(q0w, k0w, v0w, o0w, q1w, k1w,
                                              v1w, o1w, Wt);
  build_order_kernel<<<NBATCH, 1024, 0, stream>>>(mask, order, mk_g, outMk);
  qh_proj_kernel<<<dim3(2, 3), 256, 0, stream>>>(indp, Wt, q0b, qh_b);

  const short* W[3][8];
  for (int l = 0; l < 3; l++)
    for (int wi = 0; wi < 8; wi++) W[l][wi] = Wt + (size_t)(l * 8 + wi) * 16384;

  fusedA_kernel<<<1024, 256, 0, stream>>>(
      order, mk_g, cx, value, iff_w, iff_b, Z,
      W[0][1], k0b, Kb, W[0][2], v0b, Vb, W[0][4], q1b, Qb);

  for (int l = 0; l < 3; l++) {
    attn1_kernel<<<dim3(64, 8), 256, 0, stream>>>(
        qh_b + (size_t)l * 16384, Kb, Vb, mk_g, Opart, mpart, lpart);
    fusedB_kernel<<<32, 256, 0, stream>>>(
        Opart, mpart, lpart, qh_b + (size_t)l * 16384,
        W[l][3], o0b + (size_t)l * 128,
        W[l][5], k1b + (size_t)l * 128,
        W[l][6], v1b + (size_t)l * 128, khb, vhb);
    attn2_kernel<<<dim3(64, 64), 256, 0, stream>>>(Qb, khb, vhb, Ob);
    if (l < 2) {
      fusedC_kernel<<<1024, 256, 0, stream>>>(
          Ob, W[l][7], o1b + (size_t)l * 128, mk_g, Z, Z,
          W[l + 1][1], k0b + (size_t)(l + 1) * 128, Kb,
          W[l + 1][2], v0b + (size_t)(l + 1) * 128, Vb,
          W[l + 1][4], q1b + (size_t)(l + 1) * 128, Qb);
    } else {
      fusedC_kernel<<<1024, 256, 0, stream>>>(
          Ob, W[l][7], o1b + (size_t)l * 128, mk_g, Z, outZ,
          nullptr, nullptr, nullptr, nullptr, nullptr, nullptr,
          nullptr, nullptr, nullptr);
    }
  }
}